// Round 1
// baseline (4559.532 us; speedup 1.0000x reference)
//
#include <hip/hip_runtime.h>
#include <math.h>

#define BB   2
#define CC   64
#define VV   180
#define DD   384
#define WOUTN 1024
#define HIDN 256

// ---------------------------------------------------------------------------
// Kernel 1: 3x3 conv (pad=1) over [B,64,180,384] for both heads.
// Outputs channel-last: coef [B*V*D*64], fsum [B*V*D*32] (freq pairs pre-summed).
// Block = (b, y, x-tile of 64), 256 threads (x = tid&63, oc-group = tid>>6).
// ---------------------------------------------------------------------------
__global__ __launch_bounds__(256) void conv_kernel(
    const float* __restrict__ sino,
    const float* __restrict__ wc, const float* __restrict__ bc,
    const float* __restrict__ wf, const float* __restrict__ bf,
    float* __restrict__ out_coef, float* __restrict__ out_fsum)
{
    __shared__ float lds[64 * 3 * 66]; // 50.7 KB
    const int blk = blockIdx.x;
    const int xt = blk % 6;
    const int y  = (blk / 6) % VV;
    const int b  = blk / (6 * VV);
    const int x0 = xt * 64;

    // stage input patch [ic][3 rows][66 cols] with zero padding
    for (int i = threadIdx.x; i < 64 * 3 * 66; i += 256) {
        int ic  = i / 198;
        int rem = i - ic * 198;
        int r   = rem / 66;
        int xx  = rem - r * 66;
        int gy  = y + r - 1;
        int gx  = x0 + xx - 1;
        float v = 0.0f;
        if (gy >= 0 && gy < VV && gx >= 0 && gx < DD)
            v = sino[((size_t)(b * CC + ic) * VV + gy) * DD + gx];
        lds[i] = v;
    }
    __syncthreads();

    const int x   = threadIdx.x & 63;
    const int ocg = threadIdx.x >> 6; // 0..3, 16 oc each

    float ac[16], af[16];
#pragma unroll
    for (int o = 0; o < 16; ++o) { ac[o] = 0.0f; af[o] = 0.0f; }

    for (int ic = 0; ic < 64; ++ic) {
        const float* l = &lds[ic * 198];
#pragma unroll
        for (int r = 0; r < 3; ++r) {
            const float v0 = l[r * 66 + x + 0];
            const float v1 = l[r * 66 + x + 1];
            const float v2 = l[r * 66 + x + 2];
#pragma unroll
            for (int o = 0; o < 16; ++o) {
                const int oc = ocg * 16 + o;
                const float* pc = &wc[((oc * 64 + ic) * 3 + r) * 3];
                ac[o] += v0 * pc[0] + v1 * pc[1] + v2 * pc[2];
                const float* pf = &wf[((oc * 64 + ic) * 3 + r) * 3];
                af[o] += v0 * pf[0] + v1 * pf[1] + v2 * pf[2];
            }
        }
    }

    const size_t base = (size_t)(b * VV + y) * DD + (x0 + x);
    float* ocp = out_coef + base * 64 + ocg * 16;
#pragma unroll
    for (int o = 0; o < 16; ++o) ocp[o] = ac[o] + bc[ocg * 16 + o];
    float* ofp = out_fsum + base * 32 + ocg * 8;
#pragma unroll
    for (int j = 0; j < 8; ++j)
        ofp[j] = af[2 * j] + af[2 * j + 1] + bf[ocg * 16 + 2 * j] + bf[ocg * 16 + 2 * j + 1];
}

// ---------------------------------------------------------------------------
// Kernel 2: per output pixel (b,p): loop over 180 views in chunks of 6
// (12 MLP evals per chunk, register-blocked), plus bilinear back-projection.
// Deterministic accumulation (block owns its output element).
// ---------------------------------------------------------------------------
__global__ __launch_bounds__(256) void main_kernel(
    const float* __restrict__ sino, const float* __restrict__ grid,
    const float* __restrict__ sqinv, const void* __restrict__ scale_p,
    const float* __restrict__ phase_w,
    const float* __restrict__ w0, const float* __restrict__ b0,
    const float* __restrict__ w1, const float* __restrict__ b1,
    const float* __restrict__ w2, const float* __restrict__ b2,
    const float* __restrict__ ws_coef, const float* __restrict__ ws_fsum,
    float* __restrict__ out)
{
    const int tid = threadIdx.x;
    const int b = blockIdx.x >> 10;
    const int p = blockIdx.x & 1023;

    __shared__ __align__(16) float x_lds[12][64];
    __shared__ __align__(16) float h_lds[12][256];
    __shared__ float rel_s[12], len_s[12], pred_s[12];
    __shared__ int   base_s[12];
    __shared__ float part[12][4];
    __shared__ float fin[12];

    // decode scale robustly (int32 little-endian also covers int64 low word;
    // float bits of small reals are huge ints)
    int   iv = *(const int*)scale_p;
    float scale = (iv > 0 && iv < 1000000) ? (float)iv : __int_as_float(iv);
    const float cell = 2.0f / scale;
    const float S = (float)(1.0 / 384.0 + 1e-6);

    const float ph_j = cell * phase_w[tid & 31];
    const float bb0  = b0[tid];
    const float bb1  = b1[tid];
    const float ww2  = w2[tid];
    const float b2v  = b2[0];

    float q_acc = 0.0f;   // threads 0..5
    float bp_acc = 0.0f;  // threads 12..17

    for (int v0 = 0; v0 < VV; v0 += 6) {
        // ---- Phase A0: per-eval scalars + bilinear back-projection ----
        if (tid < 12) {
            const int e  = tid;
            const int vv = v0 + (e >> 1);
            const float sh = (e & 1) ? S : -S;
            const float* g = &grid[((size_t)(b * VV + vv) * WOUTN + p) * 2];
            const float gx = g[0], gy = g[1];
            float ix = ((gx + sh + 1.0f) * 384.0f - 1.0f) * 0.5f;
            ix = fminf(fmaxf(ix, 0.0f), 383.0f);
            const int xi = (int)rintf(ix);
            float iy = ((gy + 1.0f) * 180.0f - 1.0f) * 0.5f;
            iy = fminf(fmaxf(iy, 0.0f), 179.0f);
            const int yi = (int)rintf(iy);
            const float det = (2.0f * (float)xi + 1.0f) / 384.0f - 1.0f;
            const float rel = (gx - det) * 384.0f;
            rel_s[e]  = rel;
            len_s[e]  = fabsf(rel) + 1e-4f;
            base_s[e] = (b * VV + yi) * DD + xi;
        } else if (tid < 18) {
            const int t  = tid - 12;
            const int vv = v0 + t;
            const float* g = &grid[((size_t)(b * VV + vv) * WOUTN + p) * 2];
            const float gx = g[0], gy = g[1];
            float ix = ((gx + 1.0f) * 384.0f - 1.0f) * 0.5f;
            ix = fminf(fmaxf(ix, 0.0f), 383.0f);
            float iy = ((gy + 1.0f) * 180.0f - 1.0f) * 0.5f;
            iy = fminf(fmaxf(iy, 0.0f), 179.0f);
            const float xf = floorf(ix), yf = floorf(iy);
            const float wx = ix - xf, wy = iy - yf;
            const int x0i = (int)xf, y0i = (int)yf;
            const int x1i = min(x0i + 1, 383), y1i = min(y0i + 1, 179);
            const float* im = &sino[(size_t)(b * CC + 32) * VV * DD];
            const float v00 = im[y0i * DD + x0i], v01 = im[y0i * DD + x1i];
            const float v10 = im[y1i * DD + x0i], v11 = im[y1i * DD + x1i];
            const float bp = (v00 * (1.0f - wx) + v01 * wx) * (1.0f - wy)
                           + (v10 * (1.0f - wx) + v11 * wx) * wy;
            bp_acc += bp * sqinv[(size_t)(b * VV + vv) * WOUTN + p] * 10000.0f;
        }
        __syncthreads();

        // ---- Phase A1: gather conv outputs, build MLP inputs ----
        for (int i = tid; i < 12 * 32; i += 256) {
            const int e = i >> 5, j = i & 31;
            const int base = base_s[e];
            const float fs = ws_fsum[(size_t)base * 32 + j];
            const float fr = rel_s[e] * fs + ph_j;
            const float cv = cospif(fr);
            const float sv = sinpif(fr);
            const float c0 = ws_coef[(size_t)base * 64 + j];
            const float c1 = ws_coef[(size_t)base * 64 + j + 32];
            x_lds[e][j]      = c0 * cv;
            x_lds[e][j + 32] = c1 * sv;
        }
        __syncthreads();

        // ---- Layer 1: 64 -> 256 (thread = hidden unit, 12 evals blocked) ----
        float acc[12];
#pragma unroll
        for (int q = 0; q < 12; ++q) acc[q] = 0.0f;
        for (int k = 0; k < 64; k += 4) {
            const float wa = w0[(k + 0) * 256 + tid];
            const float wb = w0[(k + 1) * 256 + tid];
            const float wcv = w0[(k + 2) * 256 + tid];
            const float wd = w0[(k + 3) * 256 + tid];
#pragma unroll
            for (int q = 0; q < 12; ++q) {
                const float4 h4 = *(const float4*)&x_lds[q][k];
                acc[q] += h4.x * wa + h4.y * wb + h4.z * wcv + h4.w * wd;
            }
        }
#pragma unroll
        for (int q = 0; q < 12; ++q) h_lds[q][tid] = fmaxf(acc[q] + bb0, 0.0f);
        __syncthreads();

        // ---- Layer 2 + 3: 256 -> 256 -> 1 ----
        float acc2[12];
#pragma unroll
        for (int q = 0; q < 12; ++q) acc2[q] = 0.0f;
        for (int k = 0; k < 256; k += 4) {
            const float wa = w1[(size_t)(k + 0) * 256 + tid];
            const float wb = w1[(size_t)(k + 1) * 256 + tid];
            const float wcv = w1[(size_t)(k + 2) * 256 + tid];
            const float wd = w1[(size_t)(k + 3) * 256 + tid];
#pragma unroll
            for (int q = 0; q < 12; ++q) {
                const float4 h4 = *(const float4*)&h_lds[q][k];
                acc2[q] += h4.x * wa + h4.y * wb + h4.z * wcv + h4.w * wd;
            }
        }
        float contrib[12];
#pragma unroll
        for (int q = 0; q < 12; ++q)
            contrib[q] = fmaxf(acc2[q] + bb1, 0.0f) * ww2;

        // wave butterfly reduce (64 lanes), then cross-wave via LDS
#pragma unroll
        for (int q = 0; q < 12; ++q) {
#pragma unroll
            for (int m = 32; m >= 1; m >>= 1)
                contrib[q] += __shfl_xor(contrib[q], m, 64);
        }
        if ((tid & 63) == 0) {
            const int w = tid >> 6;
#pragma unroll
            for (int q = 0; q < 12; ++q) part[q][w] = contrib[q];
        }
        __syncthreads();
        if (tid < 12)
            pred_s[tid] = part[tid][0] + part[tid][1] + part[tid][2] + part[tid][3] + b2v;
        __syncthreads();

        // ---- blend the two shifts, accumulate ----
        if (tid < 6) {
            const float l0 = len_s[2 * tid], l1 = len_s[2 * tid + 1];
            const float tot = l0 + l1;
            const float ret = (pred_s[2 * tid] * l1 + pred_s[2 * tid + 1] * l0) / tot;
            q_acc += ret * sqinv[(size_t)(b * VV + v0 + tid) * WOUTN + p] * 10000.0f;
        }
        __syncthreads();
    }

    // ---- final deterministic combine ----
    if (tid < 6) fin[tid] = q_acc;
    if (tid >= 12 && tid < 18) fin[6 + tid - 12] = bp_acc;
    __syncthreads();
    if (tid == 0) {
        float r = 0.0f;
        for (int i = 0; i < 6; ++i) r += fin[6 + i]; // bilinear res
        for (int i = 0; i < 6; ++i) r += fin[i];     // MLP q_img
        out[(size_t)b * WOUTN + p] = r;
    }
}

extern "C" void kernel_launch(void* const* d_in, const int* in_sizes, int n_in,
                              void* d_out, int out_size, void* d_ws, size_t ws_size,
                              hipStream_t stream) {
    const float* sino    = (const float*)d_in[0];
    const float* grid    = (const float*)d_in[1];
    const float* sqinv   = (const float*)d_in[2];
    const void*  scale_p = d_in[3];
    const float* coef_w  = (const float*)d_in[4];
    const float* coef_b  = (const float*)d_in[5];
    const float* freq_w  = (const float*)d_in[6];
    const float* freq_b  = (const float*)d_in[7];
    const float* phase_w = (const float*)d_in[8];
    const float* dec_w0  = (const float*)d_in[9];
    const float* dec_b0  = (const float*)d_in[10];
    const float* dec_w1  = (const float*)d_in[11];
    const float* dec_b1  = (const float*)d_in[12];
    const float* dec_w2  = (const float*)d_in[13];
    const float* dec_b2  = (const float*)d_in[14];
    float* out = (float*)d_out;

    float* ws_coef = (float*)d_ws;                          // B*V*D*64 floats
    float* ws_fsum = ws_coef + (size_t)BB * VV * DD * 64;   // B*V*D*32 floats

    conv_kernel<<<BB * VV * (DD / 64), 256, 0, stream>>>(
        sino, coef_w, coef_b, freq_w, freq_b, ws_coef, ws_fsum);

    main_kernel<<<BB * WOUTN, 256, 0, stream>>>(
        sino, grid, sqinv, scale_p, phase_w,
        dec_w0, dec_b0, dec_w1, dec_b1, dec_w2, dec_b2,
        ws_coef, ws_fsum, out);
}

// Round 2
// 1815.662 us; speedup vs baseline: 2.5112x; 2.5112x over previous
//
#include <hip/hip_runtime.h>
#include <math.h>

#define BB   2
#define CC   64
#define VV   180
#define DD   384
#define WOUTN 1024
#define HIDN 256

typedef __attribute__((ext_vector_type(8))) short short8;   // 8 bf16 (4 VGPR)
typedef __attribute__((ext_vector_type(4))) float f32x4;    // MFMA acc

__device__ __forceinline__ unsigned short f2bf(float f) {
    unsigned int u = __float_as_uint(f);
    u += 0x7FFFu + ((u >> 16) & 1u);   // RNE
    return (unsigned short)(u >> 16);
}

// ---------------------------------------------------------------------------
// Kernel 0: convert w0 [64,256] and w1 [256,256] (f32, row-major k x n) into
// bf16 MFMA B-fragment order for 16x16x32:
//   lane l of wave w, frag (nt,ks) holds B[k=ks*32+(l>>4)*8+j][n=w*64+nt*16+(l&15)]
//   layout: [((wave*4+nt)*KSTEPS+ks)*64 + (l>>4)*16+(l&15)]*8 + j
// ---------------------------------------------------------------------------
__global__ __launch_bounds__(256) void prep_kernel(
    const float* __restrict__ w0, const float* __restrict__ w1,
    unsigned short* __restrict__ w0f, unsigned short* __restrict__ w1f)
{
    int idx = blockIdx.x * 256 + threadIdx.x;
    if (idx < 64 * 256) {
        int k = idx >> 8, n = idx & 255;
        int wave = n >> 6, nt = (n >> 4) & 3, lo = n & 15;
        int ks = k >> 5, hi = (k >> 3) & 3, j = k & 7;
        w0f[(size_t)(((wave * 4 + nt) * 2 + ks) * 64 + hi * 16 + lo) * 8 + j] =
            f2bf(w0[k * 256 + n]);
    } else if (idx < 64 * 256 + 256 * 256) {
        int i2 = idx - 64 * 256;
        int k = i2 >> 8, n = i2 & 255;
        int wave = n >> 6, nt = (n >> 4) & 3, lo = n & 15;
        int ks = k >> 5, hi = (k >> 3) & 3, j = k & 7;
        w1f[(size_t)(((wave * 4 + nt) * 8 + ks) * 64 + hi * 16 + lo) * 8 + j] =
            f2bf(w1[k * 256 + n]);
    }
}

// ---------------------------------------------------------------------------
// Kernel 1: 3x3 conv (pad=1), both heads. Outputs channel-last f32:
// coef [B*V*D*64], fsum [B*V*D*32] (freq pairs pre-summed). (unchanged)
// ---------------------------------------------------------------------------
__global__ __launch_bounds__(256) void conv_kernel(
    const float* __restrict__ sino,
    const float* __restrict__ wc, const float* __restrict__ bc,
    const float* __restrict__ wf, const float* __restrict__ bf,
    float* __restrict__ out_coef, float* __restrict__ out_fsum)
{
    __shared__ float lds[64 * 3 * 66];
    const int blk = blockIdx.x;
    const int xt = blk % 6;
    const int y  = (blk / 6) % VV;
    const int b  = blk / (6 * VV);
    const int x0 = xt * 64;

    for (int i = threadIdx.x; i < 64 * 3 * 66; i += 256) {
        int ic  = i / 198;
        int rem = i - ic * 198;
        int r   = rem / 66;
        int xx  = rem - r * 66;
        int gy  = y + r - 1;
        int gx  = x0 + xx - 1;
        float v = 0.0f;
        if (gy >= 0 && gy < VV && gx >= 0 && gx < DD)
            v = sino[((size_t)(b * CC + ic) * VV + gy) * DD + gx];
        lds[i] = v;
    }
    __syncthreads();

    const int x   = threadIdx.x & 63;
    const int ocg = threadIdx.x >> 6;

    float ac[16], af[16];
#pragma unroll
    for (int o = 0; o < 16; ++o) { ac[o] = 0.0f; af[o] = 0.0f; }

    for (int ic = 0; ic < 64; ++ic) {
        const float* l = &lds[ic * 198];
#pragma unroll
        for (int r = 0; r < 3; ++r) {
            const float v0 = l[r * 66 + x + 0];
            const float v1 = l[r * 66 + x + 1];
            const float v2 = l[r * 66 + x + 2];
#pragma unroll
            for (int o = 0; o < 16; ++o) {
                const int oc = ocg * 16 + o;
                const float* pc = &wc[((oc * 64 + ic) * 3 + r) * 3];
                ac[o] += v0 * pc[0] + v1 * pc[1] + v2 * pc[2];
                const float* pf = &wf[((oc * 64 + ic) * 3 + r) * 3];
                af[o] += v0 * pf[0] + v1 * pf[1] + v2 * pf[2];
            }
        }
    }

    const size_t base = (size_t)(b * VV + y) * DD + (x0 + x);
    float* ocp = out_coef + base * 64 + ocg * 16;
#pragma unroll
    for (int o = 0; o < 16; ++o) ocp[o] = ac[o] + bc[ocg * 16 + o];
    float* ofp = out_fsum + base * 32 + ocg * 8;
#pragma unroll
    for (int j = 0; j < 8; ++j)
        ofp[j] = af[2 * j] + af[2 * j + 1] + bf[ocg * 16 + 2 * j] + bf[ocg * 16 + 2 * j + 1];
}

// ---------------------------------------------------------------------------
// Kernel 2: one block per output pixel (b,p). 12 chunks of 16 views
// (32 MLP evals, M=32). MLP layers via mfma_f32_16x16x32_bf16:
//   layer1 [32,64]x[64,256], layer2 [32,256]x[256,256], layer3 via shfl.
// Weights held as B-fragments in registers (loaded once from prepped ws).
// x/h staged in LDS bf16 with XOR swizzle (byte ^= (row&7)<<4).
// ---------------------------------------------------------------------------
__global__ __launch_bounds__(256, 2) void main_kernel(
    const float* __restrict__ sino, const float* __restrict__ grid,
    const float* __restrict__ sqinv, const void* __restrict__ scale_p,
    const float* __restrict__ phase_w,
    const unsigned short* __restrict__ w0f, const float* __restrict__ b0,
    const unsigned short* __restrict__ w1f, const float* __restrict__ b1,
    const float* __restrict__ w2, const float* __restrict__ b2,
    const float* __restrict__ ws_coef, const float* __restrict__ ws_fsum,
    float* __restrict__ out)
{
    const int tid  = threadIdx.x;
    const int b    = blockIdx.x >> 10;
    const int p    = blockIdx.x & 1023;
    const int wave = tid >> 6;
    const int lane = tid & 63;
    const int lo   = lane & 15;
    const int g    = lane >> 4;

    __shared__ __align__(16) unsigned short x_lds[32 * 64];    // 4 KB
    __shared__ __align__(16) unsigned short h_lds[32 * 256];   // 16 KB
    __shared__ float rel_s[32], len_s[32];
    __shared__ int   base_s[32];
    __shared__ float part[32][4];
    __shared__ float fin[32];

    int   iv = *(const int*)scale_p;
    float scale = (iv > 0 && iv < 1000000) ? (float)iv : __int_as_float(iv);
    const float cell = 2.0f / scale;
    const float S = (float)(1.0 / 384.0 + 1e-6);
    const float ph_j = cell * phase_w[tid & 31];

    // ---- load weight B-fragments into registers (per wave: 64 columns) ----
    short8 w0q[4][2], w1q[4][8];
#pragma unroll
    for (int nt = 0; nt < 4; ++nt)
#pragma unroll
        for (int ks = 0; ks < 2; ++ks)
            w0q[nt][ks] = *(const short8*)(w0f + (size_t)(((wave * 4 + nt) * 2 + ks) * 64 + lane) * 8);
#pragma unroll
    for (int nt = 0; nt < 4; ++nt)
#pragma unroll
        for (int ks = 0; ks < 8; ++ks)
            w1q[nt][ks] = *(const short8*)(w1f + (size_t)(((wave * 4 + nt) * 8 + ks) * 64 + lane) * 8);

    float b0q[4], b1q[4], w2q[4];
#pragma unroll
    for (int nt = 0; nt < 4; ++nt) {
        const int n = wave * 64 + nt * 16 + lo;
        b0q[nt] = b0[n]; b1q[nt] = b1[n]; w2q[nt] = w2[n];
    }
    const float b2v = b2[0];

    float q_acc = 0.0f;   // tid 0..15 (per view in chunk)
    float bp_acc = 0.0f;  // tid 32..47

    for (int v0 = 0; v0 < VV; v0 += 16) {
        // ---- Phase A: per-eval scalars + bilinear back-projection ----
        if (tid < 32) {
            const int e = tid, vl = e >> 1, vv = v0 + vl;
            if (vv < VV) {
                const float sh = (e & 1) ? S : -S;
                const float* gp = &grid[((size_t)(b * VV + vv) * WOUTN + p) * 2];
                const float gx = gp[0], gy = gp[1];
                float ix = ((gx + sh + 1.0f) * 384.0f - 1.0f) * 0.5f;
                ix = fminf(fmaxf(ix, 0.0f), 383.0f);
                const int xi = (int)rintf(ix);
                float iy = ((gy + 1.0f) * 180.0f - 1.0f) * 0.5f;
                iy = fminf(fmaxf(iy, 0.0f), 179.0f);
                const int yi = (int)rintf(iy);
                const float det = (2.0f * (float)xi + 1.0f) / 384.0f - 1.0f;
                const float rel = (gx - det) * 384.0f;
                rel_s[e] = rel;
                len_s[e] = fabsf(rel) + 1e-4f;
                base_s[e] = (b * VV + yi) * DD + xi;
            } else {
                rel_s[e] = 0.0f; len_s[e] = 1.0f; base_s[e] = 0;
            }
        } else if (tid < 48) {
            const int t = tid - 32, vv = v0 + t;
            if (vv < VV) {
                const float* gp = &grid[((size_t)(b * VV + vv) * WOUTN + p) * 2];
                const float gx = gp[0], gy = gp[1];
                float ix = ((gx + 1.0f) * 384.0f - 1.0f) * 0.5f;
                ix = fminf(fmaxf(ix, 0.0f), 383.0f);
                float iy = ((gy + 1.0f) * 180.0f - 1.0f) * 0.5f;
                iy = fminf(fmaxf(iy, 0.0f), 179.0f);
                const float xf = floorf(ix), yf = floorf(iy);
                const float wx = ix - xf, wy = iy - yf;
                const int x0i = (int)xf, y0i = (int)yf;
                const int x1i = min(x0i + 1, 383), y1i = min(y0i + 1, 179);
                const float* im = &sino[(size_t)(b * CC + 32) * VV * DD];
                const float v00 = im[y0i * DD + x0i], v01 = im[y0i * DD + x1i];
                const float v10 = im[y1i * DD + x0i], v11 = im[y1i * DD + x1i];
                const float bp = (v00 * (1.0f - wx) + v01 * wx) * (1.0f - wy)
                               + (v10 * (1.0f - wx) + v11 * wx) * wy;
                bp_acc += bp * sqinv[(size_t)(b * VV + vv) * WOUTN + p] * 10000.0f;
            }
        }
        __syncthreads();

        // ---- Phase B: gather conv outputs, build x [32 evals][64] bf16 ----
#pragma unroll
        for (int it = 0; it < 4; ++it) {
            const int e = (tid >> 5) + it * 8;
            const int j = tid & 31;
            const int base = base_s[e];
            const float fs = ws_fsum[(size_t)base * 32 + j];
            const float fr = rel_s[e] * fs + ph_j;
            const float cv = cospif(fr);
            const float sv = sinpif(fr);
            const float c0 = ws_coef[(size_t)base * 64 + j];
            const float c1 = ws_coef[(size_t)base * 64 + j + 32];
            const int swz = (e & 7) << 4;
            x_lds[((e * 128 + j * 2) ^ swz) >> 1]        = f2bf(c0 * cv);
            x_lds[((e * 128 + (j + 32) * 2) ^ swz) >> 1] = f2bf(c1 * sv);
        }
        __syncthreads();

        // ---- Layer 1: [32,64] x [64,256] -> h ----
        f32x4 acc1[2][4];
#pragma unroll
        for (int mt = 0; mt < 2; ++mt)
#pragma unroll
            for (int nt = 0; nt < 4; ++nt) acc1[mt][nt] = (f32x4)0.0f;

        short8 ax[2][2];
#pragma unroll
        for (int mt = 0; mt < 2; ++mt)
#pragma unroll
            for (int ks = 0; ks < 2; ++ks) {
                const int row = mt * 16 + lo;
                const int byte = (row * 128 + ks * 64 + g * 16) ^ ((row & 7) << 4);
                ax[mt][ks] = *(const short8*)((const char*)x_lds + byte);
            }
#pragma unroll
        for (int mt = 0; mt < 2; ++mt)
#pragma unroll
            for (int nt = 0; nt < 4; ++nt) {
                acc1[mt][nt] = __builtin_amdgcn_mfma_f32_16x16x32_bf16(ax[mt][0], w0q[nt][0], acc1[mt][nt], 0, 0, 0);
                acc1[mt][nt] = __builtin_amdgcn_mfma_f32_16x16x32_bf16(ax[mt][1], w0q[nt][1], acc1[mt][nt], 0, 0, 0);
            }

        // bias + relu + cvt, write h (bf16, swizzled)
#pragma unroll
        for (int mt = 0; mt < 2; ++mt)
#pragma unroll
            for (int nt = 0; nt < 4; ++nt) {
                const int n = wave * 64 + nt * 16 + lo;
#pragma unroll
                for (int r = 0; r < 4; ++r) {
                    const int e = mt * 16 + g * 4 + r;
                    const float hv = fmaxf(acc1[mt][nt][r] + b0q[nt], 0.0f);
                    h_lds[((e * 512 + n * 2) ^ ((e & 7) << 4)) >> 1] = f2bf(hv);
                }
            }
        __syncthreads();

        // ---- Layer 2: [32,256] x [256,256] ----
        f32x4 acc2[2][4];
#pragma unroll
        for (int mt = 0; mt < 2; ++mt)
#pragma unroll
            for (int nt = 0; nt < 4; ++nt) acc2[mt][nt] = (f32x4)0.0f;

#pragma unroll
        for (int ks = 0; ks < 8; ++ks) {
            short8 ah[2];
#pragma unroll
            for (int mt = 0; mt < 2; ++mt) {
                const int row = mt * 16 + lo;
                const int byte = (row * 512 + ks * 64 + g * 16) ^ ((row & 7) << 4);
                ah[mt] = *(const short8*)((const char*)h_lds + byte);
            }
#pragma unroll
            for (int mt = 0; mt < 2; ++mt)
#pragma unroll
                for (int nt = 0; nt < 4; ++nt)
                    acc2[mt][nt] = __builtin_amdgcn_mfma_f32_16x16x32_bf16(ah[mt], w1q[nt][ks], acc2[mt][nt], 0, 0, 0);
        }

        // ---- Layer 3: relu, dot with w2, reduce over 256 cols ----
        float s[2][4];
#pragma unroll
        for (int mt = 0; mt < 2; ++mt)
#pragma unroll
            for (int r = 0; r < 4; ++r) s[mt][r] = 0.0f;
#pragma unroll
        for (int mt = 0; mt < 2; ++mt)
#pragma unroll
            for (int nt = 0; nt < 4; ++nt)
#pragma unroll
                for (int r = 0; r < 4; ++r)
                    s[mt][r] += fmaxf(acc2[mt][nt][r] + b1q[nt], 0.0f) * w2q[nt];
        // reduce across the 16 lanes of each l>>4 group (cols)
#pragma unroll
        for (int mt = 0; mt < 2; ++mt)
#pragma unroll
            for (int r = 0; r < 4; ++r) {
#pragma unroll
                for (int m = 8; m >= 1; m >>= 1)
                    s[mt][r] += __shfl_xor(s[mt][r], m, 64);
            }
        if (lo == 0) {
#pragma unroll
            for (int mt = 0; mt < 2; ++mt)
#pragma unroll
                for (int r = 0; r < 4; ++r)
                    part[mt * 16 + g * 4 + r][wave] = s[mt][r];
        }
        __syncthreads();

        // ---- blend the two shifts, accumulate q_img ----
        if (tid < 16) {
            const int vv = v0 + tid;
            if (vv < VV) {
                const int e0 = 2 * tid, e1 = 2 * tid + 1;
                const float p0 = part[e0][0] + part[e0][1] + part[e0][2] + part[e0][3] + b2v;
                const float p1 = part[e1][0] + part[e1][1] + part[e1][2] + part[e1][3] + b2v;
                const float l0 = len_s[e0], l1 = len_s[e1];
                const float ret = (p0 * l1 + p1 * l0) / (l0 + l1);
                q_acc += ret * sqinv[(size_t)(b * VV + vv) * WOUTN + p] * 10000.0f;
            }
        }
        __syncthreads();   // protect rel_s/base_s/part before next chunk
    }

    // ---- final deterministic combine ----
    if (tid < 16) fin[tid] = q_acc;
    if (tid >= 32 && tid < 48) fin[16 + tid - 32] = bp_acc;
    __syncthreads();
    if (tid == 0) {
        float r = 0.0f;
        for (int i = 16; i < 32; ++i) r += fin[i];  // bilinear res
        for (int i = 0; i < 16; ++i) r += fin[i];   // MLP q_img
        out[(size_t)b * WOUTN + p] = r;
    }
}

extern "C" void kernel_launch(void* const* d_in, const int* in_sizes, int n_in,
                              void* d_out, int out_size, void* d_ws, size_t ws_size,
                              hipStream_t stream) {
    const float* sino    = (const float*)d_in[0];
    const float* grid    = (const float*)d_in[1];
    const float* sqinv   = (const float*)d_in[2];
    const void*  scale_p = d_in[3];
    const float* coef_w  = (const float*)d_in[4];
    const float* coef_b  = (const float*)d_in[5];
    const float* freq_w  = (const float*)d_in[6];
    const float* freq_b  = (const float*)d_in[7];
    const float* phase_w = (const float*)d_in[8];
    const float* dec_w0  = (const float*)d_in[9];
    const float* dec_b0  = (const float*)d_in[10];
    const float* dec_w1  = (const float*)d_in[11];
    const float* dec_b1  = (const float*)d_in[12];
    const float* dec_w2  = (const float*)d_in[13];
    const float* dec_b2  = (const float*)d_in[14];
    float* out = (float*)d_out;

    float* ws_coef = (float*)d_ws;                          // B*V*D*64 f32
    float* ws_fsum = ws_coef + (size_t)BB * VV * DD * 64;   // B*V*D*32 f32
    unsigned short* w0f = (unsigned short*)(ws_fsum + (size_t)BB * VV * DD * 32);
    unsigned short* w1f = w0f + 64 * 256;

    prep_kernel<<<(64 * 256 + 256 * 256 + 255) / 256, 256, 0, stream>>>(
        dec_w0, dec_w1, w0f, w1f);

    conv_kernel<<<BB * VV * (DD / 64), 256, 0, stream>>>(
        sino, coef_w, coef_b, freq_w, freq_b, ws_coef, ws_fsum);

    main_kernel<<<BB * WOUTN, 256, 0, stream>>>(
        sino, grid, sqinv, scale_p, phase_w,
        w0f, dec_b0, w1f, dec_b1, dec_w2, dec_b2,
        ws_coef, ws_fsum, out);
}

// Round 3
// 646.158 us; speedup vs baseline: 7.0564x; 2.8099x over previous
//
#include <hip/hip_runtime.h>
#include <math.h>

#define BB   2
#define CC   64
#define VV   180
#define DD   384
#define WOUTN 1024
#define HIDN 256

typedef __attribute__((ext_vector_type(8))) short short8;   // 8 bf16 (4 VGPR)
typedef __attribute__((ext_vector_type(4))) float f32x4;    // MFMA acc

__device__ __forceinline__ unsigned short f2bf(float f) {
    unsigned int u = __float_as_uint(f);
    u += 0x7FFFu + ((u >> 16) & 1u);   // RNE
    return (unsigned short)(u >> 16);
}

// ---------------------------------------------------------------------------
// Kernel 0: weight prep.
//  - w0 [64,256], w1 [256,256] -> bf16 MFMA B-fragment order (MLP)
//  - coef_w/freq_w [64oc,64ic,3,3] -> combined conv B [K=576][N=128] fragments
//    k = tap*64+ic (tap=r*3+t), n: 0-63 coef oc, 64-127 freq oc.
//  frag addr: [((ks*NT + nt)*64 + hi*16 + lo)*8 + j], k=ks*32+hi*8+j, n=nt*16+lo
// ---------------------------------------------------------------------------
__global__ __launch_bounds__(256) void prep_kernel(
    const float* __restrict__ w0, const float* __restrict__ w1,
    const float* __restrict__ wc, const float* __restrict__ wf,
    unsigned short* __restrict__ w0f, unsigned short* __restrict__ w1f,
    unsigned short* __restrict__ wcf)
{
    int idx = blockIdx.x * 256 + threadIdx.x;
    if (idx < 64 * 256) {
        int k = idx >> 8, n = idx & 255;
        int wave = n >> 6, nt = (n >> 4) & 3, lo = n & 15;
        int ks = k >> 5, hi = (k >> 3) & 3, j = k & 7;
        w0f[(size_t)(((wave * 4 + nt) * 2 + ks) * 64 + hi * 16 + lo) * 8 + j] =
            f2bf(w0[k * 256 + n]);
    } else if (idx < 64 * 256 + 256 * 256) {
        int i2 = idx - 64 * 256;
        int k = i2 >> 8, n = i2 & 255;
        int wave = n >> 6, nt = (n >> 4) & 3, lo = n & 15;
        int ks = k >> 5, hi = (k >> 3) & 3, j = k & 7;
        w1f[(size_t)(((wave * 4 + nt) * 8 + ks) * 64 + hi * 16 + lo) * 8 + j] =
            f2bf(w1[k * 256 + n]);
    } else if (idx < 64 * 256 + 256 * 256 + 576 * 128) {
        int i3 = idx - (64 * 256 + 256 * 256);
        int k = i3 >> 7, n = i3 & 127;
        int tap = k >> 6, ic = k & 63;
        int r = tap / 3, t = tap - r * 3;
        int head = n >> 6, oc = n & 63;
        float val = (head ? wf : wc)[((oc * 64 + ic) * 3 + r) * 3 + t];
        int ks = k >> 5, hi = (k >> 3) & 3, j = k & 7;
        int nt = n >> 4, lo = n & 15;
        wcf[(size_t)((ks * 8 + nt) * 64 + hi * 16 + lo) * 8 + j] = f2bf(val);
    }
}

// ---------------------------------------------------------------------------
// Kernel 1: transpose sinogram [b,c,y,x] f32 -> channel-last bf16 [b,y,x,c]
// ---------------------------------------------------------------------------
__global__ __launch_bounds__(256) void transpose_kernel(
    const float* __restrict__ sino, unsigned short* __restrict__ sino_cl)
{
    __shared__ float tile[64][65];
    const int blk = blockIdx.x;
    const int xt = blk % 6;
    const int y  = (blk / 6) % VV;
    const int b  = blk / (6 * VV);
    const int x0 = xt * 64;

    const int x  = threadIdx.x & 63;
    const int cq = threadIdx.x >> 6;
#pragma unroll
    for (int cr = 0; cr < 16; ++cr) {
        const int c = cr * 4 + cq;
        tile[c][x] = sino[((size_t)(b * CC + c) * VV + y) * DD + x0 + x];
    }
    __syncthreads();

    const int xw = threadIdx.x >> 2;
    const int cg = threadIdx.x & 3;
    __align__(16) unsigned short vals[16];
#pragma unroll
    for (int i = 0; i < 16; ++i) vals[i] = f2bf(tile[cg * 16 + i][xw]);
    unsigned short* dst = sino_cl + ((size_t)(b * VV + y) * DD + x0 + xw) * 64 + cg * 16;
    *(short8*)dst       = *(const short8*)&vals[0];
    *((short8*)dst + 1) = *(const short8*)&vals[8];
}

// ---------------------------------------------------------------------------
// Kernel 2: conv as implicit GEMM via MFMA.
// Block = (b, y, 64-wide x tile). M=64 pixels, N=128 (coef|freq), K=576.
// A tile [3][66][64ic] bf16 in LDS, XOR-swizzled (byte ^= (x&7)<<4).
// Weights streamed from prepped fragment buffer (L2-resident broadcast).
// ---------------------------------------------------------------------------
#define SWZ(x) (((x) & 7) << 4)

__global__ __launch_bounds__(256) void conv_mfma_kernel(
    const unsigned short* __restrict__ sino_cl,
    const unsigned short* __restrict__ wcf,
    const float* __restrict__ bc, const float* __restrict__ bf,
    float* __restrict__ out_coef, float* __restrict__ out_fsum)
{
    __shared__ __align__(16) unsigned short a_lds[3 * 66 * 64];   // 25344 B
    const int blk = blockIdx.x;
    const int xt = blk % 6;
    const int y  = (blk / 6) % VV;
    const int b  = blk / (6 * VV);
    const int x0 = xt * 64;
    const int tid  = threadIdx.x;
    const int wave = tid >> 6;
    const int lane = tid & 63;
    const int lo   = lane & 15;
    const int g    = lane >> 4;

    // ---- stage A: 1584 chunks of 16B (8 ic each), zero-padded, swizzled ----
    for (int cc = tid; cc < 1584; cc += 256) {
        const int r   = cc / 528;            // 528 = 66*8
        const int rem = cc - r * 528;
        const int x   = rem >> 3;
        const int icg = rem & 7;
        const int gy  = y + r - 1;
        const int gx  = x0 + x - 1;
        short8 v = (short8)0;
        if (gy >= 0 && gy < VV && gx >= 0 && gx < DD)
            v = *(const short8*)(sino_cl + ((size_t)(b * VV + gy) * DD + gx) * 64 + icg * 8);
        const int dst = ((r * 66 + x) * 128 + icg * 16) ^ SWZ(x);
        *(short8*)((char*)a_lds + dst) = v;
    }
    __syncthreads();

    f32x4 acc[4][2];
#pragma unroll
    for (int m = 0; m < 4; ++m) {
        acc[m][0] = (f32x4)0.0f;
        acc[m][1] = (f32x4)0.0f;
    }

#pragma unroll
    for (int ks = 0; ks < 18; ++ks) {
        const int tap = ks >> 1;
        const int r = tap / 3, t = tap - (tap / 3) * 3;   // compile-time (unrolled)
        const short8 wq0 = *(const short8*)(wcf + (size_t)((ks * 8 + wave * 2 + 0) * 64 + lane) * 8);
        const short8 wq1 = *(const short8*)(wcf + (size_t)((ks * 8 + wave * 2 + 1) * 64 + lane) * 8);
        short8 aq[4];
#pragma unroll
        for (int m = 0; m < 4; ++m) {
            const int x = m * 16 + lo + t;
            const int byte = ((r * 66 + x) * 128 + ((ks & 1) * 64 + g * 16)) ^ SWZ(x);
            aq[m] = *(const short8*)((const char*)a_lds + byte);
        }
#pragma unroll
        for (int m = 0; m < 4; ++m) {
            acc[m][0] = __builtin_amdgcn_mfma_f32_16x16x32_bf16(aq[m], wq0, acc[m][0], 0, 0, 0);
            acc[m][1] = __builtin_amdgcn_mfma_f32_16x16x32_bf16(aq[m], wq1, acc[m][1], 0, 0, 0);
        }
    }

    // ---- epilogue: C[pixel][col], col = nt16 block; row = g*4 + ri ----
    const size_t pixbase = (size_t)(b * VV + y) * DD + x0;
    if (wave < 2) {
        // coef head: oc = wave*32 + nt*16 + lo
#pragma unroll
        for (int nt = 0; nt < 2; ++nt) {
            const int oc = wave * 32 + nt * 16 + lo;
            const float bias = bc[oc];
#pragma unroll
            for (int m = 0; m < 4; ++m)
#pragma unroll
                for (int ri = 0; ri < 4; ++ri) {
                    const int pix = m * 16 + g * 4 + ri;
                    out_coef[(pixbase + pix) * 64 + oc] = acc[m][nt][ri] + bias;
                }
        }
    } else {
        // freq head: ocf = (wave-2)*32 + nt*16 + lo; pair-sum via shfl
#pragma unroll
        for (int nt = 0; nt < 2; ++nt) {
            const int ocf = (wave - 2) * 32 + nt * 16 + lo;
            const float bsum = bf[ocf] + bf[ocf ^ 1];
#pragma unroll
            for (int m = 0; m < 4; ++m)
#pragma unroll
                for (int ri = 0; ri < 4; ++ri) {
                    const float v  = acc[m][nt][ri];
                    const float vp = __shfl_xor(v, 1, 64);
                    if ((lo & 1) == 0) {
                        const int pix = m * 16 + g * 4 + ri;
                        out_fsum[(pixbase + pix) * 32 + (ocf >> 1)] = v + vp + bsum;
                    }
                }
        }
    }
}

// ---------------------------------------------------------------------------
// Kernel 3: one block per output pixel (b,p). 12 chunks of 16 views
// (32 MLP evals, M=32). MLP layers via mfma_f32_16x16x32_bf16. (unchanged)
// ---------------------------------------------------------------------------
__global__ __launch_bounds__(256, 2) void main_kernel(
    const float* __restrict__ sino, const float* __restrict__ grid,
    const float* __restrict__ sqinv, const void* __restrict__ scale_p,
    const float* __restrict__ phase_w,
    const unsigned short* __restrict__ w0f, const float* __restrict__ b0,
    const unsigned short* __restrict__ w1f, const float* __restrict__ b1,
    const float* __restrict__ w2, const float* __restrict__ b2,
    const float* __restrict__ ws_coef, const float* __restrict__ ws_fsum,
    float* __restrict__ out)
{
    const int tid  = threadIdx.x;
    const int b    = blockIdx.x >> 10;
    const int p    = blockIdx.x & 1023;
    const int wave = tid >> 6;
    const int lane = tid & 63;
    const int lo   = lane & 15;
    const int g    = lane >> 4;

    __shared__ __align__(16) unsigned short x_lds[32 * 64];    // 4 KB
    __shared__ __align__(16) unsigned short h_lds[32 * 256];   // 16 KB
    __shared__ float rel_s[32], len_s[32];
    __shared__ int   base_s[32];
    __shared__ float part[32][4];
    __shared__ float fin[32];

    int   iv = *(const int*)scale_p;
    float scale = (iv > 0 && iv < 1000000) ? (float)iv : __int_as_float(iv);
    const float cell = 2.0f / scale;
    const float S = (float)(1.0 / 384.0 + 1e-6);
    const float ph_j = cell * phase_w[tid & 31];

    short8 w0q[4][2], w1q[4][8];
#pragma unroll
    for (int nt = 0; nt < 4; ++nt)
#pragma unroll
        for (int ks = 0; ks < 2; ++ks)
            w0q[nt][ks] = *(const short8*)(w0f + (size_t)(((wave * 4 + nt) * 2 + ks) * 64 + lane) * 8);
#pragma unroll
    for (int nt = 0; nt < 4; ++nt)
#pragma unroll
        for (int ks = 0; ks < 8; ++ks)
            w1q[nt][ks] = *(const short8*)(w1f + (size_t)(((wave * 4 + nt) * 8 + ks) * 64 + lane) * 8);

    float b0q[4], b1q[4], w2q[4];
#pragma unroll
    for (int nt = 0; nt < 4; ++nt) {
        const int n = wave * 64 + nt * 16 + lo;
        b0q[nt] = b0[n]; b1q[nt] = b1[n]; w2q[nt] = w2[n];
    }
    const float b2v = b2[0];

    float q_acc = 0.0f;   // tid 0..15
    float bp_acc = 0.0f;  // tid 32..47

    for (int v0 = 0; v0 < VV; v0 += 16) {
        // ---- Phase A ----
        if (tid < 32) {
            const int e = tid, vl = e >> 1, vv = v0 + vl;
            if (vv < VV) {
                const float sh = (e & 1) ? S : -S;
                const float* gp = &grid[((size_t)(b * VV + vv) * WOUTN + p) * 2];
                const float gx = gp[0], gy = gp[1];
                float ix = ((gx + sh + 1.0f) * 384.0f - 1.0f) * 0.5f;
                ix = fminf(fmaxf(ix, 0.0f), 383.0f);
                const int xi = (int)rintf(ix);
                float iy = ((gy + 1.0f) * 180.0f - 1.0f) * 0.5f;
                iy = fminf(fmaxf(iy, 0.0f), 179.0f);
                const int yi = (int)rintf(iy);
                const float det = (2.0f * (float)xi + 1.0f) / 384.0f - 1.0f;
                const float rel = (gx - det) * 384.0f;
                rel_s[e] = rel;
                len_s[e] = fabsf(rel) + 1e-4f;
                base_s[e] = (b * VV + yi) * DD + xi;
            } else {
                rel_s[e] = 0.0f; len_s[e] = 1.0f; base_s[e] = 0;
            }
        } else if (tid < 48) {
            const int t = tid - 32, vv = v0 + t;
            if (vv < VV) {
                const float* gp = &grid[((size_t)(b * VV + vv) * WOUTN + p) * 2];
                const float gx = gp[0], gy = gp[1];
                float ix = ((gx + 1.0f) * 384.0f - 1.0f) * 0.5f;
                ix = fminf(fmaxf(ix, 0.0f), 383.0f);
                float iy = ((gy + 1.0f) * 180.0f - 1.0f) * 0.5f;
                iy = fminf(fmaxf(iy, 0.0f), 179.0f);
                const float xf = floorf(ix), yf = floorf(iy);
                const float wx = ix - xf, wy = iy - yf;
                const int x0i = (int)xf, y0i = (int)yf;
                const int x1i = min(x0i + 1, 383), y1i = min(y0i + 1, 179);
                const float* im = &sino[(size_t)(b * CC + 32) * VV * DD];
                const float v00 = im[y0i * DD + x0i], v01 = im[y0i * DD + x1i];
                const float v10 = im[y1i * DD + x0i], v11 = im[y1i * DD + x1i];
                const float bp = (v00 * (1.0f - wx) + v01 * wx) * (1.0f - wy)
                               + (v10 * (1.0f - wx) + v11 * wx) * wy;
                bp_acc += bp * sqinv[(size_t)(b * VV + vv) * WOUTN + p] * 10000.0f;
            }
        }
        __syncthreads();

        // ---- Phase B: gather conv outputs, build x ----
#pragma unroll
        for (int it = 0; it < 4; ++it) {
            const int e = (tid >> 5) + it * 8;
            const int j = tid & 31;
            const int base = base_s[e];
            const float fs = ws_fsum[(size_t)base * 32 + j];
            const float fr = rel_s[e] * fs + ph_j;
            const float cv = cospif(fr);
            const float sv = sinpif(fr);
            const float c0 = ws_coef[(size_t)base * 64 + j];
            const float c1 = ws_coef[(size_t)base * 64 + j + 32];
            const int swz = (e & 7) << 4;
            x_lds[((e * 128 + j * 2) ^ swz) >> 1]        = f2bf(c0 * cv);
            x_lds[((e * 128 + (j + 32) * 2) ^ swz) >> 1] = f2bf(c1 * sv);
        }
        __syncthreads();

        // ---- Layer 1 ----
        f32x4 acc1[2][4];
#pragma unroll
        for (int mt = 0; mt < 2; ++mt)
#pragma unroll
            for (int nt = 0; nt < 4; ++nt) acc1[mt][nt] = (f32x4)0.0f;

        short8 ax[2][2];
#pragma unroll
        for (int mt = 0; mt < 2; ++mt)
#pragma unroll
            for (int ks = 0; ks < 2; ++ks) {
                const int row = mt * 16 + lo;
                const int byte = (row * 128 + ks * 64 + g * 16) ^ ((row & 7) << 4);
                ax[mt][ks] = *(const short8*)((const char*)x_lds + byte);
            }
#pragma unroll
        for (int mt = 0; mt < 2; ++mt)
#pragma unroll
            for (int nt = 0; nt < 4; ++nt) {
                acc1[mt][nt] = __builtin_amdgcn_mfma_f32_16x16x32_bf16(ax[mt][0], w0q[nt][0], acc1[mt][nt], 0, 0, 0);
                acc1[mt][nt] = __builtin_amdgcn_mfma_f32_16x16x32_bf16(ax[mt][1], w0q[nt][1], acc1[mt][nt], 0, 0, 0);
            }

#pragma unroll
        for (int mt = 0; mt < 2; ++mt)
#pragma unroll
            for (int nt = 0; nt < 4; ++nt) {
                const int n = wave * 64 + nt * 16 + lo;
#pragma unroll
                for (int r = 0; r < 4; ++r) {
                    const int e = mt * 16 + g * 4 + r;
                    const float hv = fmaxf(acc1[mt][nt][r] + b0q[nt], 0.0f);
                    h_lds[((e * 512 + n * 2) ^ ((e & 7) << 4)) >> 1] = f2bf(hv);
                }
            }
        __syncthreads();

        // ---- Layer 2 ----
        f32x4 acc2[2][4];
#pragma unroll
        for (int mt = 0; mt < 2; ++mt)
#pragma unroll
            for (int nt = 0; nt < 4; ++nt) acc2[mt][nt] = (f32x4)0.0f;

#pragma unroll
        for (int ks = 0; ks < 8; ++ks) {
            short8 ah[2];
#pragma unroll
            for (int mt = 0; mt < 2; ++mt) {
                const int row = mt * 16 + lo;
                const int byte = (row * 512 + ks * 64 + g * 16) ^ ((row & 7) << 4);
                ah[mt] = *(const short8*)((const char*)h_lds + byte);
            }
#pragma unroll
            for (int mt = 0; mt < 2; ++mt)
#pragma unroll
                for (int nt = 0; nt < 4; ++nt)
                    acc2[mt][nt] = __builtin_amdgcn_mfma_f32_16x16x32_bf16(ah[mt], w1q[nt][ks], acc2[mt][nt], 0, 0, 0);
        }

        // ---- Layer 3 ----
        float s[2][4];
#pragma unroll
        for (int mt = 0; mt < 2; ++mt)
#pragma unroll
            for (int r = 0; r < 4; ++r) s[mt][r] = 0.0f;
#pragma unroll
        for (int mt = 0; mt < 2; ++mt)
#pragma unroll
            for (int nt = 0; nt < 4; ++nt)
#pragma unroll
                for (int r = 0; r < 4; ++r)
                    s[mt][r] += fmaxf(acc2[mt][nt][r] + b1q[nt], 0.0f) * w2q[nt];
#pragma unroll
        for (int mt = 0; mt < 2; ++mt)
#pragma unroll
            for (int r = 0; r < 4; ++r) {
#pragma unroll
                for (int m = 8; m >= 1; m >>= 1)
                    s[mt][r] += __shfl_xor(s[mt][r], m, 64);
            }
        if (lo == 0) {
#pragma unroll
            for (int mt = 0; mt < 2; ++mt)
#pragma unroll
                for (int r = 0; r < 4; ++r)
                    part[mt * 16 + g * 4 + r][wave] = s[mt][r];
        }
        __syncthreads();

        if (tid < 16) {
            const int vv = v0 + tid;
            if (vv < VV) {
                const int e0 = 2 * tid, e1 = 2 * tid + 1;
                const float p0 = part[e0][0] + part[e0][1] + part[e0][2] + part[e0][3] + b2v;
                const float p1 = part[e1][0] + part[e1][1] + part[e1][2] + part[e1][3] + b2v;
                const float l0 = len_s[e0], l1 = len_s[e1];
                const float ret = (p0 * l1 + p1 * l0) / (l0 + l1);
                q_acc += ret * sqinv[(size_t)(b * VV + vv) * WOUTN + p] * 10000.0f;
            }
        }
        __syncthreads();
    }

    if (tid < 16) fin[tid] = q_acc;
    if (tid >= 32 && tid < 48) fin[16 + tid - 32] = bp_acc;
    __syncthreads();
    if (tid == 0) {
        float r = 0.0f;
        for (int i = 16; i < 32; ++i) r += fin[i];
        for (int i = 0; i < 16; ++i) r += fin[i];
        out[(size_t)b * WOUTN + p] = r;
    }
}

extern "C" void kernel_launch(void* const* d_in, const int* in_sizes, int n_in,
                              void* d_out, int out_size, void* d_ws, size_t ws_size,
                              hipStream_t stream) {
    const float* sino    = (const float*)d_in[0];
    const float* grid    = (const float*)d_in[1];
    const float* sqinv   = (const float*)d_in[2];
    const void*  scale_p = d_in[3];
    const float* coef_w  = (const float*)d_in[4];
    const float* coef_b  = (const float*)d_in[5];
    const float* freq_w  = (const float*)d_in[6];
    const float* freq_b  = (const float*)d_in[7];
    const float* phase_w = (const float*)d_in[8];
    const float* dec_w0  = (const float*)d_in[9];
    const float* dec_b0  = (const float*)d_in[10];
    const float* dec_w1  = (const float*)d_in[11];
    const float* dec_b1  = (const float*)d_in[12];
    const float* dec_w2  = (const float*)d_in[13];
    const float* dec_b2  = (const float*)d_in[14];
    float* out = (float*)d_out;

    float* ws_coef = (float*)d_ws;                          // B*V*D*64 f32
    float* ws_fsum = ws_coef + (size_t)BB * VV * DD * 64;   // B*V*D*32 f32
    unsigned short* w0f = (unsigned short*)(ws_fsum + (size_t)BB * VV * DD * 32);
    unsigned short* w1f = w0f + 64 * 256;
    unsigned short* wcf = w1f + 256 * 256;
    unsigned short* sino_cl = wcf + 576 * 128;              // B*V*D*64 bf16

    prep_kernel<<<(64 * 256 + 256 * 256 + 576 * 128 + 255) / 256, 256, 0, stream>>>(
        dec_w0, dec_w1, coef_w, freq_w, w0f, w1f, wcf);

    transpose_kernel<<<BB * VV * (DD / 64), 256, 0, stream>>>(sino, sino_cl);

    conv_mfma_kernel<<<BB * VV * (DD / 64), 256, 0, stream>>>(
        sino_cl, wcf, coef_b, freq_b, ws_coef, ws_fsum);

    main_kernel<<<BB * WOUTN, 256, 0, stream>>>(
        sino, grid, sqinv, scale_p, phase_w,
        w0f, dec_b0, w1f, dec_b1, dec_w2, dec_b2,
        ws_coef, ws_fsum, out);
}

// Round 4
// 530.450 us; speedup vs baseline: 8.5956x; 1.2181x over previous
//
#include <hip/hip_runtime.h>
#include <math.h>

#define BB   2
#define CC   64
#define VV   180
#define DD   384
#define WOUTN 1024
#define HIDN 256
#define VSPLIT 4

typedef __attribute__((ext_vector_type(8))) short short8;   // 8 bf16 (4 VGPR)
typedef __attribute__((ext_vector_type(4))) float f32x4;    // MFMA acc

__device__ __forceinline__ unsigned short f2bf(float f) {
    unsigned int u = __float_as_uint(f);
    u += 0x7FFFu + ((u >> 16) & 1u);   // RNE
    return (unsigned short)(u >> 16);
}

// ---------------------------------------------------------------------------
// Kernel 0: weight prep (MLP w0/w1 + combined conv weights -> bf16 fragments)
// ---------------------------------------------------------------------------
__global__ __launch_bounds__(256) void prep_kernel(
    const float* __restrict__ w0, const float* __restrict__ w1,
    const float* __restrict__ wc, const float* __restrict__ wf,
    unsigned short* __restrict__ w0f, unsigned short* __restrict__ w1f,
    unsigned short* __restrict__ wcf)
{
    int idx = blockIdx.x * 256 + threadIdx.x;
    if (idx < 64 * 256) {
        int k = idx >> 8, n = idx & 255;
        int wave = n >> 6, nt = (n >> 4) & 3, lo = n & 15;
        int ks = k >> 5, hi = (k >> 3) & 3, j = k & 7;
        w0f[(size_t)(((wave * 4 + nt) * 2 + ks) * 64 + hi * 16 + lo) * 8 + j] =
            f2bf(w0[k * 256 + n]);
    } else if (idx < 64 * 256 + 256 * 256) {
        int i2 = idx - 64 * 256;
        int k = i2 >> 8, n = i2 & 255;
        int wave = n >> 6, nt = (n >> 4) & 3, lo = n & 15;
        int ks = k >> 5, hi = (k >> 3) & 3, j = k & 7;
        w1f[(size_t)(((wave * 4 + nt) * 8 + ks) * 64 + hi * 16 + lo) * 8 + j] =
            f2bf(w1[k * 256 + n]);
    } else if (idx < 64 * 256 + 256 * 256 + 576 * 128) {
        int i3 = idx - (64 * 256 + 256 * 256);
        int k = i3 >> 7, n = i3 & 127;
        int tap = k >> 6, ic = k & 63;
        int r = tap / 3, t = tap - r * 3;
        int head = n >> 6, oc = n & 63;
        float val = (head ? wf : wc)[((oc * 64 + ic) * 3 + r) * 3 + t];
        int ks = k >> 5, hi = (k >> 3) & 3, j = k & 7;
        int nt = n >> 4, lo = n & 15;
        wcf[(size_t)((ks * 8 + nt) * 64 + hi * 16 + lo) * 8 + j] = f2bf(val);
    }
}

// ---------------------------------------------------------------------------
// Kernel 1: transpose sinogram [b,c,y,x] f32 -> channel-last bf16 [b,y,x,c]
// ---------------------------------------------------------------------------
__global__ __launch_bounds__(256) void transpose_kernel(
    const float* __restrict__ sino, unsigned short* __restrict__ sino_cl)
{
    __shared__ float tile[64][65];
    const int blk = blockIdx.x;
    const int xt = blk % 6;
    const int y  = (blk / 6) % VV;
    const int b  = blk / (6 * VV);
    const int x0 = xt * 64;

    const int x  = threadIdx.x & 63;
    const int cq = threadIdx.x >> 6;
#pragma unroll
    for (int cr = 0; cr < 16; ++cr) {
        const int c = cr * 4 + cq;
        tile[c][x] = sino[((size_t)(b * CC + c) * VV + y) * DD + x0 + x];
    }
    __syncthreads();

    const int xw = threadIdx.x >> 2;
    const int cg = threadIdx.x & 3;
    __align__(16) unsigned short vals[16];
#pragma unroll
    for (int i = 0; i < 16; ++i) vals[i] = f2bf(tile[cg * 16 + i][xw]);
    unsigned short* dst = sino_cl + ((size_t)(b * VV + y) * DD + x0 + xw) * 64 + cg * 16;
    *(short8*)dst       = *(const short8*)&vals[0];
    *((short8*)dst + 1) = *(const short8*)&vals[8];
}

// ---------------------------------------------------------------------------
// Kernel 2: conv as implicit GEMM via MFMA. (unchanged from R3)
// ---------------------------------------------------------------------------
#define SWZ(x) (((x) & 7) << 4)

__global__ __launch_bounds__(256) void conv_mfma_kernel(
    const unsigned short* __restrict__ sino_cl,
    const unsigned short* __restrict__ wcf,
    const float* __restrict__ bc, const float* __restrict__ bf,
    float* __restrict__ out_coef, float* __restrict__ out_fsum)
{
    __shared__ __align__(16) unsigned short a_lds[3 * 66 * 64];
    const int blk = blockIdx.x;
    const int xt = blk % 6;
    const int y  = (blk / 6) % VV;
    const int b  = blk / (6 * VV);
    const int x0 = xt * 64;
    const int tid  = threadIdx.x;
    const int wave = tid >> 6;
    const int lane = tid & 63;
    const int lo   = lane & 15;
    const int g    = lane >> 4;

    for (int cc = tid; cc < 1584; cc += 256) {
        const int r   = cc / 528;
        const int rem = cc - r * 528;
        const int x   = rem >> 3;
        const int icg = rem & 7;
        const int gy  = y + r - 1;
        const int gx  = x0 + x - 1;
        short8 v = (short8)0;
        if (gy >= 0 && gy < VV && gx >= 0 && gx < DD)
            v = *(const short8*)(sino_cl + ((size_t)(b * VV + gy) * DD + gx) * 64 + icg * 8);
        const int dst = ((r * 66 + x) * 128 + icg * 16) ^ SWZ(x);
        *(short8*)((char*)a_lds + dst) = v;
    }
    __syncthreads();

    f32x4 acc[4][2];
#pragma unroll
    for (int m = 0; m < 4; ++m) {
        acc[m][0] = (f32x4)0.0f;
        acc[m][1] = (f32x4)0.0f;
    }

#pragma unroll
    for (int ks = 0; ks < 18; ++ks) {
        const int tap = ks >> 1;
        const int r = tap / 3, t = tap - (tap / 3) * 3;
        const short8 wq0 = *(const short8*)(wcf + (size_t)((ks * 8 + wave * 2 + 0) * 64 + lane) * 8);
        const short8 wq1 = *(const short8*)(wcf + (size_t)((ks * 8 + wave * 2 + 1) * 64 + lane) * 8);
        short8 aq[4];
#pragma unroll
        for (int m = 0; m < 4; ++m) {
            const int x = m * 16 + lo + t;
            const int byte = ((r * 66 + x) * 128 + ((ks & 1) * 64 + g * 16)) ^ SWZ(x);
            aq[m] = *(const short8*)((const char*)a_lds + byte);
        }
#pragma unroll
        for (int m = 0; m < 4; ++m) {
            acc[m][0] = __builtin_amdgcn_mfma_f32_16x16x32_bf16(aq[m], wq0, acc[m][0], 0, 0, 0);
            acc[m][1] = __builtin_amdgcn_mfma_f32_16x16x32_bf16(aq[m], wq1, acc[m][1], 0, 0, 0);
        }
    }

    const size_t pixbase = (size_t)(b * VV + y) * DD + x0;
    if (wave < 2) {
#pragma unroll
        for (int nt = 0; nt < 2; ++nt) {
            const int oc = wave * 32 + nt * 16 + lo;
            const float bias = bc[oc];
#pragma unroll
            for (int m = 0; m < 4; ++m)
#pragma unroll
                for (int ri = 0; ri < 4; ++ri) {
                    const int pix = m * 16 + g * 4 + ri;
                    out_coef[(pixbase + pix) * 64 + oc] = acc[m][nt][ri] + bias;
                }
        }
    } else {
#pragma unroll
        for (int nt = 0; nt < 2; ++nt) {
            const int ocf = (wave - 2) * 32 + nt * 16 + lo;
            const float bsum = bf[ocf] + bf[ocf ^ 1];
#pragma unroll
            for (int m = 0; m < 4; ++m)
#pragma unroll
                for (int ri = 0; ri < 4; ++ri) {
                    const float v  = acc[m][nt][ri];
                    const float vp = __shfl_xor(v, 1, 64);
                    if ((lo & 1) == 0) {
                        const int pix = m * 16 + g * 4 + ri;
                        out_fsum[(pixbase + pix) * 32 + (ocf >> 1)] = v + vp + bsum;
                    }
                }
        }
    }
}

// ---------------------------------------------------------------------------
// Kernel 3: block = (b, p, z). Each z handles 3 of the 12 view-chunks
// (chunks 3z..3z+2), writes one partial float to ws_part[(b*1024+p)*4+z].
// ---------------------------------------------------------------------------
__global__ __launch_bounds__(256, 2) void main_kernel(
    const float* __restrict__ sino, const float* __restrict__ grid,
    const float* __restrict__ sqinv, const void* __restrict__ scale_p,
    const float* __restrict__ phase_w,
    const unsigned short* __restrict__ w0f, const float* __restrict__ b0,
    const unsigned short* __restrict__ w1f, const float* __restrict__ b1,
    const float* __restrict__ w2, const float* __restrict__ b2,
    const float* __restrict__ ws_coef, const float* __restrict__ ws_fsum,
    float* __restrict__ ws_part)
{
    const int tid  = threadIdx.x;
    const int z    = blockIdx.x & (VSPLIT - 1);
    const int bp   = blockIdx.x >> 2;          // b*1024 + p
    const int b    = bp >> 10;
    const int p    = bp & 1023;
    const int wave = tid >> 6;
    const int lane = tid & 63;
    const int lo   = lane & 15;
    const int g    = lane >> 4;

    __shared__ __align__(16) unsigned short x_lds[32 * 64];    // 4 KB
    __shared__ __align__(16) unsigned short h_lds[32 * 256];   // 16 KB
    __shared__ float rel_s[32], len_s[32];
    __shared__ int   base_s[32];
    __shared__ float part[32][4];
    __shared__ float fin[32];

    int   iv = *(const int*)scale_p;
    float scale = (iv > 0 && iv < 1000000) ? (float)iv : __int_as_float(iv);
    const float cell = 2.0f / scale;
    const float S = (float)(1.0 / 384.0 + 1e-6);
    const float ph_j = cell * phase_w[tid & 31];

    short8 w0q[4][2], w1q[4][8];
#pragma unroll
    for (int nt = 0; nt < 4; ++nt)
#pragma unroll
        for (int ks = 0; ks < 2; ++ks)
            w0q[nt][ks] = *(const short8*)(w0f + (size_t)(((wave * 4 + nt) * 2 + ks) * 64 + lane) * 8);
#pragma unroll
    for (int nt = 0; nt < 4; ++nt)
#pragma unroll
        for (int ks = 0; ks < 8; ++ks)
            w1q[nt][ks] = *(const short8*)(w1f + (size_t)(((wave * 4 + nt) * 8 + ks) * 64 + lane) * 8);

    float b0q[4], b1q[4], w2q[4];
#pragma unroll
    for (int nt = 0; nt < 4; ++nt) {
        const int n = wave * 64 + nt * 16 + lo;
        b0q[nt] = b0[n]; b1q[nt] = b1[n]; w2q[nt] = w2[n];
    }
    const float b2v = b2[0];

    float q_acc = 0.0f;   // tid 0..15
    float bp_acc = 0.0f;  // tid 32..47

#pragma unroll
    for (int ci = 0; ci < 3; ++ci) {
        const int v0 = (z * 3 + ci) * 16;

        // ---- Phase A: per-eval scalars + bilinear back-projection ----
        if (tid < 32) {
            const int e = tid, vl = e >> 1, vv = v0 + vl;
            if (vv < VV) {
                const float sh = (e & 1) ? S : -S;
                const float* gp = &grid[((size_t)(b * VV + vv) * WOUTN + p) * 2];
                const float gx = gp[0], gy = gp[1];
                float ix = ((gx + sh + 1.0f) * 384.0f - 1.0f) * 0.5f;
                ix = fminf(fmaxf(ix, 0.0f), 383.0f);
                const int xi = (int)rintf(ix);
                float iy = ((gy + 1.0f) * 180.0f - 1.0f) * 0.5f;
                iy = fminf(fmaxf(iy, 0.0f), 179.0f);
                const int yi = (int)rintf(iy);
                const float det = (2.0f * (float)xi + 1.0f) / 384.0f - 1.0f;
                const float rel = (gx - det) * 384.0f;
                rel_s[e] = rel;
                len_s[e] = fabsf(rel) + 1e-4f;
                base_s[e] = (b * VV + yi) * DD + xi;
            } else {
                rel_s[e] = 0.0f; len_s[e] = 1.0f; base_s[e] = 0;
            }
        } else if (tid < 48) {
            const int t = tid - 32, vv = v0 + t;
            if (vv < VV) {
                const float* gp = &grid[((size_t)(b * VV + vv) * WOUTN + p) * 2];
                const float gx = gp[0], gy = gp[1];
                float ix = ((gx + 1.0f) * 384.0f - 1.0f) * 0.5f;
                ix = fminf(fmaxf(ix, 0.0f), 383.0f);
                float iy = ((gy + 1.0f) * 180.0f - 1.0f) * 0.5f;
                iy = fminf(fmaxf(iy, 0.0f), 179.0f);
                const float xf = floorf(ix), yf = floorf(iy);
                const float wx = ix - xf, wy = iy - yf;
                const int x0i = (int)xf, y0i = (int)yf;
                const int x1i = min(x0i + 1, 383), y1i = min(y0i + 1, 179);
                const float* im = &sino[(size_t)(b * CC + 32) * VV * DD];
                const float v00 = im[y0i * DD + x0i], v01 = im[y0i * DD + x1i];
                const float v10 = im[y1i * DD + x0i], v11 = im[y1i * DD + x1i];
                const float bpv = (v00 * (1.0f - wx) + v01 * wx) * (1.0f - wy)
                                + (v10 * (1.0f - wx) + v11 * wx) * wy;
                bp_acc += bpv * sqinv[(size_t)(b * VV + vv) * WOUTN + p] * 10000.0f;
            }
        }
        __syncthreads();

        // ---- Phase B: gather conv outputs, build x ----
#pragma unroll
        for (int it = 0; it < 4; ++it) {
            const int e = (tid >> 5) + it * 8;
            const int j = tid & 31;
            const int base = base_s[e];
            const float fs = ws_fsum[(size_t)base * 32 + j];
            const float fr = rel_s[e] * fs + ph_j;
            const float cv = cospif(fr);
            const float sv = sinpif(fr);
            const float c0 = ws_coef[(size_t)base * 64 + j];
            const float c1 = ws_coef[(size_t)base * 64 + j + 32];
            const int swz = (e & 7) << 4;
            x_lds[((e * 128 + j * 2) ^ swz) >> 1]        = f2bf(c0 * cv);
            x_lds[((e * 128 + (j + 32) * 2) ^ swz) >> 1] = f2bf(c1 * sv);
        }
        __syncthreads();

        // ---- Layer 1 ----
        f32x4 acc1[2][4];
#pragma unroll
        for (int mt = 0; mt < 2; ++mt)
#pragma unroll
            for (int nt = 0; nt < 4; ++nt) acc1[mt][nt] = (f32x4)0.0f;

        short8 ax[2][2];
#pragma unroll
        for (int mt = 0; mt < 2; ++mt)
#pragma unroll
            for (int ks = 0; ks < 2; ++ks) {
                const int row = mt * 16 + lo;
                const int byte = (row * 128 + ks * 64 + g * 16) ^ ((row & 7) << 4);
                ax[mt][ks] = *(const short8*)((const char*)x_lds + byte);
            }
#pragma unroll
        for (int mt = 0; mt < 2; ++mt)
#pragma unroll
            for (int nt = 0; nt < 4; ++nt) {
                acc1[mt][nt] = __builtin_amdgcn_mfma_f32_16x16x32_bf16(ax[mt][0], w0q[nt][0], acc1[mt][nt], 0, 0, 0);
                acc1[mt][nt] = __builtin_amdgcn_mfma_f32_16x16x32_bf16(ax[mt][1], w0q[nt][1], acc1[mt][nt], 0, 0, 0);
            }

#pragma unroll
        for (int mt = 0; mt < 2; ++mt)
#pragma unroll
            for (int nt = 0; nt < 4; ++nt) {
                const int n = wave * 64 + nt * 16 + lo;
#pragma unroll
                for (int r = 0; r < 4; ++r) {
                    const int e = mt * 16 + g * 4 + r;
                    const float hv = fmaxf(acc1[mt][nt][r] + b0q[nt], 0.0f);
                    h_lds[((e * 512 + n * 2) ^ ((e & 7) << 4)) >> 1] = f2bf(hv);
                }
            }
        __syncthreads();

        // ---- Layer 2 ----
        f32x4 acc2[2][4];
#pragma unroll
        for (int mt = 0; mt < 2; ++mt)
#pragma unroll
            for (int nt = 0; nt < 4; ++nt) acc2[mt][nt] = (f32x4)0.0f;

#pragma unroll
        for (int ks = 0; ks < 8; ++ks) {
            short8 ah[2];
#pragma unroll
            for (int mt = 0; mt < 2; ++mt) {
                const int row = mt * 16 + lo;
                const int byte = (row * 512 + ks * 64 + g * 16) ^ ((row & 7) << 4);
                ah[mt] = *(const short8*)((const char*)h_lds + byte);
            }
#pragma unroll
            for (int mt = 0; mt < 2; ++mt)
#pragma unroll
                for (int nt = 0; nt < 4; ++nt)
                    acc2[mt][nt] = __builtin_amdgcn_mfma_f32_16x16x32_bf16(ah[mt], w1q[nt][ks], acc2[mt][nt], 0, 0, 0);
        }

        // ---- Layer 3 ----
        float s[2][4];
#pragma unroll
        for (int mt = 0; mt < 2; ++mt)
#pragma unroll
            for (int r = 0; r < 4; ++r) s[mt][r] = 0.0f;
#pragma unroll
        for (int mt = 0; mt < 2; ++mt)
#pragma unroll
            for (int nt = 0; nt < 4; ++nt)
#pragma unroll
                for (int r = 0; r < 4; ++r)
                    s[mt][r] += fmaxf(acc2[mt][nt][r] + b1q[nt], 0.0f) * w2q[nt];
#pragma unroll
        for (int mt = 0; mt < 2; ++mt)
#pragma unroll
            for (int r = 0; r < 4; ++r) {
#pragma unroll
                for (int m = 8; m >= 1; m >>= 1)
                    s[mt][r] += __shfl_xor(s[mt][r], m, 64);
            }
        if (lo == 0) {
#pragma unroll
            for (int mt = 0; mt < 2; ++mt)
#pragma unroll
                for (int r = 0; r < 4; ++r)
                    part[mt * 16 + g * 4 + r][wave] = s[mt][r];
        }
        __syncthreads();

        if (tid < 16) {
            const int vv = v0 + tid;
            if (vv < VV) {
                const int e0 = 2 * tid, e1 = 2 * tid + 1;
                const float p0 = part[e0][0] + part[e0][1] + part[e0][2] + part[e0][3] + b2v;
                const float p1 = part[e1][0] + part[e1][1] + part[e1][2] + part[e1][3] + b2v;
                const float l0 = len_s[e0], l1 = len_s[e1];
                const float ret = (p0 * l1 + p1 * l0) / (l0 + l1);
                q_acc += ret * sqinv[(size_t)(b * VV + vv) * WOUTN + p] * 10000.0f;
            }
        }
        __syncthreads();
    }

    // ---- write this z-slice's partial (deterministic) ----
    if (tid < 16) fin[tid] = q_acc;
    if (tid >= 32 && tid < 48) fin[16 + tid - 32] = bp_acc;
    __syncthreads();
    if (tid == 0) {
        float r = 0.0f;
        for (int i = 16; i < 32; ++i) r += fin[i];
        for (int i = 0; i < 16; ++i) r += fin[i];
        ws_part[(size_t)bp * VSPLIT + z] = r;
    }
}

// ---------------------------------------------------------------------------
// Kernel 4: sum the VSPLIT partials per output element (fixed order).
// ---------------------------------------------------------------------------
__global__ __launch_bounds__(256) void reduce_kernel(
    const float* __restrict__ ws_part, float* __restrict__ out)
{
    const int i = blockIdx.x * 256 + threadIdx.x;
    if (i < BB * WOUTN) {
        const float* pp = ws_part + (size_t)i * VSPLIT;
        out[i] = ((pp[0] + pp[1]) + pp[2]) + pp[3];
    }
}

extern "C" void kernel_launch(void* const* d_in, const int* in_sizes, int n_in,
                              void* d_out, int out_size, void* d_ws, size_t ws_size,
                              hipStream_t stream) {
    const float* sino    = (const float*)d_in[0];
    const float* grid    = (const float*)d_in[1];
    const float* sqinv   = (const float*)d_in[2];
    const void*  scale_p = d_in[3];
    const float* coef_w  = (const float*)d_in[4];
    const float* coef_b  = (const float*)d_in[5];
    const float* freq_w  = (const float*)d_in[6];
    const float* freq_b  = (const float*)d_in[7];
    const float* phase_w = (const float*)d_in[8];
    const float* dec_w0  = (const float*)d_in[9];
    const float* dec_b0  = (const float*)d_in[10];
    const float* dec_w1  = (const float*)d_in[11];
    const float* dec_b1  = (const float*)d_in[12];
    const float* dec_w2  = (const float*)d_in[13];
    const float* dec_b2  = (const float*)d_in[14];
    float* out = (float*)d_out;

    float* ws_coef = (float*)d_ws;                          // B*V*D*64 f32
    float* ws_fsum = ws_coef + (size_t)BB * VV * DD * 64;   // B*V*D*32 f32
    unsigned short* w0f = (unsigned short*)(ws_fsum + (size_t)BB * VV * DD * 32);
    unsigned short* w1f = w0f + 64 * 256;
    unsigned short* wcf = w1f + 256 * 256;
    unsigned short* sino_cl = wcf + 576 * 128;              // B*V*D*64 bf16
    float* ws_part = (float*)(sino_cl + (size_t)BB * VV * DD * 64);  // B*1024*VSPLIT f32

    prep_kernel<<<(64 * 256 + 256 * 256 + 576 * 128 + 255) / 256, 256, 0, stream>>>(
        dec_w0, dec_w1, coef_w, freq_w, w0f, w1f, wcf);

    transpose_kernel<<<BB * VV * (DD / 64), 256, 0, stream>>>(sino, sino_cl);

    conv_mfma_kernel<<<BB * VV * (DD / 64), 256, 0, stream>>>(
        sino_cl, wcf, coef_b, freq_b, ws_coef, ws_fsum);

    main_kernel<<<BB * WOUTN * VSPLIT, 256, 0, stream>>>(
        sino, grid, sqinv, scale_p, phase_w,
        w0f, dec_b0, w1f, dec_b1, dec_w2, dec_b2,
        ws_coef, ws_fsum, ws_part);

    reduce_kernel<<<(BB * WOUTN + 255) / 256, 256, 0, stream>>>(ws_part, out);
}

// Round 5
// 256.713 us; speedup vs baseline: 17.7612x; 2.0663x over previous
//
#include <hip/hip_runtime.h>
#include <math.h>

#define BB    2
#define CC    64
#define VV    180
#define DD    384
#define WOUTN 1024
#define HIDN  256
#define NSLICE 4
#define VSL   45                       // views per slice
#define EVSL  (VSL * BB * WOUTN * 2)   // evals per slice = 184320

typedef __attribute__((ext_vector_type(8))) short short8;   // 8 bf16
typedef __attribute__((ext_vector_type(4))) float f32x4;    // MFMA acc

__device__ __forceinline__ unsigned short f2bf(float f) {
    unsigned int u = __float_as_uint(f);
    u += 0x7FFFu + ((u >> 16) & 1u);   // RNE
    return (unsigned short)(u >> 16);
}
__device__ __forceinline__ float bf2f(unsigned short s) {
    return __uint_as_float(((unsigned int)s) << 16);
}

// ---------------------------------------------------------------------------
// Kernel 0: weight prep (MLP w0/w1 + combined conv weights -> bf16 fragments)
// ---------------------------------------------------------------------------
__global__ __launch_bounds__(256) void prep_kernel(
    const float* __restrict__ w0, const float* __restrict__ w1,
    const float* __restrict__ wc, const float* __restrict__ wf,
    unsigned short* __restrict__ w0f, unsigned short* __restrict__ w1f,
    unsigned short* __restrict__ wcf)
{
    int idx = blockIdx.x * 256 + threadIdx.x;
    if (idx < 64 * 256) {
        int k = idx >> 8, n = idx & 255;
        int wave = n >> 6, nt = (n >> 4) & 3, lo = n & 15;
        int ks = k >> 5, hi = (k >> 3) & 3, j = k & 7;
        w0f[(size_t)(((wave * 4 + nt) * 2 + ks) * 64 + hi * 16 + lo) * 8 + j] =
            f2bf(w0[k * 256 + n]);
    } else if (idx < 64 * 256 + 256 * 256) {
        int i2 = idx - 64 * 256;
        int k = i2 >> 8, n = i2 & 255;
        int wave = n >> 6, nt = (n >> 4) & 3, lo = n & 15;
        int ks = k >> 5, hi = (k >> 3) & 3, j = k & 7;
        w1f[(size_t)(((wave * 4 + nt) * 8 + ks) * 64 + hi * 16 + lo) * 8 + j] =
            f2bf(w1[k * 256 + n]);
    } else if (idx < 64 * 256 + 256 * 256 + 576 * 128) {
        int i3 = idx - (64 * 256 + 256 * 256);
        int k = i3 >> 7, n = i3 & 127;
        int tap = k >> 6, ic = k & 63;
        int r = tap / 3, t = tap - r * 3;
        int head = n >> 6, oc = n & 63;
        float val = (head ? wf : wc)[((oc * 64 + ic) * 3 + r) * 3 + t];
        int ks = k >> 5, hi = (k >> 3) & 3, j = k & 7;
        int nt = n >> 4, lo = n & 15;
        wcf[(size_t)((ks * 8 + nt) * 64 + hi * 16 + lo) * 8 + j] = f2bf(val);
    }
}

// ---------------------------------------------------------------------------
// Kernel 1: transpose sinogram [b,c,y,x] f32 -> channel-last bf16 [b,y,x,c]
// ---------------------------------------------------------------------------
__global__ __launch_bounds__(256) void transpose_kernel(
    const float* __restrict__ sino, unsigned short* __restrict__ sino_cl)
{
    __shared__ float tile[64][65];
    const int blk = blockIdx.x;
    const int xt = blk % 6;
    const int y  = (blk / 6) % VV;
    const int b  = blk / (6 * VV);
    const int x0 = xt * 64;

    const int x  = threadIdx.x & 63;
    const int cq = threadIdx.x >> 6;
#pragma unroll
    for (int cr = 0; cr < 16; ++cr) {
        const int c = cr * 4 + cq;
        tile[c][x] = sino[((size_t)(b * CC + c) * VV + y) * DD + x0 + x];
    }
    __syncthreads();

    const int xw = threadIdx.x >> 2;
    const int cg = threadIdx.x & 3;
    __align__(16) unsigned short vals[16];
#pragma unroll
    for (int i = 0; i < 16; ++i) vals[i] = f2bf(tile[cg * 16 + i][xw]);
    unsigned short* dst = sino_cl + ((size_t)(b * VV + y) * DD + x0 + xw) * 64 + cg * 16;
    *(short8*)dst       = *(const short8*)&vals[0];
    *((short8*)dst + 1) = *(const short8*)&vals[8];
}

// ---------------------------------------------------------------------------
// Kernel 2: conv as implicit GEMM via MFMA. coef out is now bf16.
// ---------------------------------------------------------------------------
#define SWZ(x) (((x) & 7) << 4)

__global__ __launch_bounds__(256) void conv_mfma_kernel(
    const unsigned short* __restrict__ sino_cl,
    const unsigned short* __restrict__ wcf,
    const float* __restrict__ bc, const float* __restrict__ bf,
    unsigned short* __restrict__ out_coef, float* __restrict__ out_fsum)
{
    __shared__ __align__(16) unsigned short a_lds[3 * 66 * 64];
    const int blk = blockIdx.x;
    const int xt = blk % 6;
    const int y  = (blk / 6) % VV;
    const int b  = blk / (6 * VV);
    const int x0 = xt * 64;
    const int tid  = threadIdx.x;
    const int wave = tid >> 6;
    const int lane = tid & 63;
    const int lo   = lane & 15;
    const int g    = lane >> 4;

    for (int cc = tid; cc < 1584; cc += 256) {
        const int r   = cc / 528;
        const int rem = cc - r * 528;
        const int x   = rem >> 3;
        const int icg = rem & 7;
        const int gy  = y + r - 1;
        const int gx  = x0 + x - 1;
        short8 v = (short8)0;
        if (gy >= 0 && gy < VV && gx >= 0 && gx < DD)
            v = *(const short8*)(sino_cl + ((size_t)(b * VV + gy) * DD + gx) * 64 + icg * 8);
        const int dst = ((r * 66 + x) * 128 + icg * 16) ^ SWZ(x);
        *(short8*)((char*)a_lds + dst) = v;
    }
    __syncthreads();

    f32x4 acc[4][2];
#pragma unroll
    for (int m = 0; m < 4; ++m) {
        acc[m][0] = (f32x4)0.0f;
        acc[m][1] = (f32x4)0.0f;
    }

#pragma unroll
    for (int ks = 0; ks < 18; ++ks) {
        const int tap = ks >> 1;
        const int r = tap / 3, t = tap - (tap / 3) * 3;
        const short8 wq0 = *(const short8*)(wcf + (size_t)((ks * 8 + wave * 2 + 0) * 64 + lane) * 8);
        const short8 wq1 = *(const short8*)(wcf + (size_t)((ks * 8 + wave * 2 + 1) * 64 + lane) * 8);
        short8 aq[4];
#pragma unroll
        for (int m = 0; m < 4; ++m) {
            const int x = m * 16 + lo + t;
            const int byte = ((r * 66 + x) * 128 + ((ks & 1) * 64 + g * 16)) ^ SWZ(x);
            aq[m] = *(const short8*)((const char*)a_lds + byte);
        }
#pragma unroll
        for (int m = 0; m < 4; ++m) {
            acc[m][0] = __builtin_amdgcn_mfma_f32_16x16x32_bf16(aq[m], wq0, acc[m][0], 0, 0, 0);
            acc[m][1] = __builtin_amdgcn_mfma_f32_16x16x32_bf16(aq[m], wq1, acc[m][1], 0, 0, 0);
        }
    }

    const size_t pixbase = (size_t)(b * VV + y) * DD + x0;
    if (wave < 2) {
#pragma unroll
        for (int nt = 0; nt < 2; ++nt) {
            const int oc = wave * 32 + nt * 16 + lo;
            const float bias = bc[oc];
#pragma unroll
            for (int m = 0; m < 4; ++m)
#pragma unroll
                for (int ri = 0; ri < 4; ++ri) {
                    const int pix = m * 16 + g * 4 + ri;
                    out_coef[(pixbase + pix) * 64 + oc] = f2bf(acc[m][nt][ri] + bias);
                }
        }
    } else {
#pragma unroll
        for (int nt = 0; nt < 2; ++nt) {
            const int ocf = (wave - 2) * 32 + nt * 16 + lo;
            const float bsum = bf[ocf] + bf[ocf ^ 1];
#pragma unroll
            for (int m = 0; m < 4; ++m)
#pragma unroll
                for (int ri = 0; ri < 4; ++ri) {
                    const float v  = acc[m][nt][ri];
                    const float vp = __shfl_xor(v, 1, 64);
                    if ((lo & 1) == 0) {
                        const int pix = m * 16 + g * 4 + ri;
                        out_fsum[(pixbase + pix) * 32 + (ocf >> 1)] = v + vp + bsum;
                    }
                }
        }
    }
}

// ---------------------------------------------------------------------------
// Kernel 3: xbuild — gather + trig, 4 threads per eval, no barriers.
// eval-local index el = ((vl*BB + b)*WOUTN + p)*2 + sh, vl in [0,VSL).
// Writes X[el][64] bf16.
// ---------------------------------------------------------------------------
__global__ __launch_bounds__(256) void xbuild_kernel(
    const float* __restrict__ grid, const float* __restrict__ fsum,
    const unsigned short* __restrict__ coef_bf,
    const void* __restrict__ scale_p, const float* __restrict__ phase_w,
    unsigned short* __restrict__ X, int vbase)
{
    const int t  = blockIdx.x * 256 + threadIdx.x;
    const int el = t >> 2;
    const int q  = t & 3;

    const int sh = el & 1;
    const int p  = (el >> 1) & 1023;
    const int b  = (el >> 11) & 1;
    const int vl = el >> 12;
    const int v  = vbase + vl;

    int   iv = *(const int*)scale_p;
    float scale = (iv > 0 && iv < 1000000) ? (float)iv : __int_as_float(iv);
    const float cell = 2.0f / scale;
    const float S = (float)(1.0 / 384.0 + 1e-6);
    const float shv = sh ? S : -S;

    const float* gp = &grid[((size_t)(b * VV + v) * WOUTN + p) * 2];
    const float gx = gp[0], gy = gp[1];
    float ix = ((gx + shv + 1.0f) * 384.0f - 1.0f) * 0.5f;
    ix = fminf(fmaxf(ix, 0.0f), 383.0f);
    const int xi = (int)rintf(ix);
    float iy = ((gy + 1.0f) * 180.0f - 1.0f) * 0.5f;
    iy = fminf(fmaxf(iy, 0.0f), 179.0f);
    const int yi = (int)rintf(iy);
    const float det = (2.0f * (float)xi + 1.0f) / 384.0f - 1.0f;
    const float rel = (gx - det) * 384.0f;
    const int base = (b * VV + yi) * DD + xi;

    const int j0 = q * 8;
    const float4 fsa = *(const float4*)(fsum + (size_t)base * 32 + j0);
    const float4 fsb = *(const float4*)(fsum + (size_t)base * 32 + j0 + 4);
    const short8 c0 = *(const short8*)(coef_bf + (size_t)base * 64 + j0);
    const short8 c1 = *(const short8*)(coef_bf + (size_t)base * 64 + 32 + j0);
    const float4 pha = *(const float4*)(phase_w + j0);
    const float4 phb = *(const float4*)(phase_w + j0 + 4);

    float fs[8] = {fsa.x, fsa.y, fsa.z, fsa.w, fsb.x, fsb.y, fsb.z, fsb.w};
    float ph[8] = {pha.x, pha.y, pha.z, pha.w, phb.x, phb.y, phb.z, phb.w};

    __align__(16) unsigned short xc[8], xs[8];
#pragma unroll
    for (int jj = 0; jj < 8; ++jj) {
        const float fr = rel * fs[jj] + cell * ph[jj];
        xc[jj] = f2bf(bf2f((unsigned short)c0[jj]) * cospif(fr));
        xs[jj] = f2bf(bf2f((unsigned short)c1[jj]) * sinpif(fr));
    }
    *(short8*)(X + (size_t)el * 64 + j0)      = *(const short8*)xc;
    *(short8*)(X + (size_t)el * 64 + 32 + j0) = *(const short8*)xs;
}

// ---------------------------------------------------------------------------
// Kernel 4: mlp — batched GEMM, M-tile 64/block, 4 waves (wave = 64 N-cols).
// X tile -> LDS (swizzled); layer1 K=64; h [64][256] bf16 LDS; layer2 K=256
// (w1 frags streamed from L2); layer3 dot+reduce; pred[m0+row] f32.
// ---------------------------------------------------------------------------
__global__ __launch_bounds__(256, 2) void mlp_kernel(
    const unsigned short* __restrict__ X,
    const unsigned short* __restrict__ w0f, const float* __restrict__ b0,
    const unsigned short* __restrict__ w1f, const float* __restrict__ b1,
    const float* __restrict__ w2, const float* __restrict__ b2,
    float* __restrict__ pred)
{
    const int tid  = threadIdx.x;
    const int wave = tid >> 6;
    const int lane = tid & 63;
    const int lo   = lane & 15;
    const int g    = lane >> 4;
    const int m0   = blockIdx.x * 64;

    __shared__ __align__(16) unsigned short x_lds[64 * 64];    // 8 KB
    __shared__ __align__(16) unsigned short h_lds[64 * 256];   // 32 KB
    __shared__ float part[64][4];

    // ---- stage X tile (swizzled) ----
#pragma unroll
    for (int it = 0; it < 2; ++it) {
        const int idx = it * 256 + tid;
        const int row = idx >> 3;
        const int c   = idx & 7;
        const short8 vv = *(const short8*)(X + (size_t)(m0 + row) * 64 + c * 8);
        const int dst = (row * 128 + c * 16) ^ SWZ(row);
        *(short8*)((char*)x_lds + dst) = vv;
    }

    // ---- weights (layer1 kept in regs; layer2 streamed) ----
    short8 w0q[4][2];
#pragma unroll
    for (int nt = 0; nt < 4; ++nt)
#pragma unroll
        for (int ks = 0; ks < 2; ++ks)
            w0q[nt][ks] = *(const short8*)(w0f + (size_t)(((wave * 4 + nt) * 2 + ks) * 64 + lane) * 8);

    float b0q[4], b1q[4], w2q[4];
#pragma unroll
    for (int nt = 0; nt < 4; ++nt) {
        const int n = wave * 64 + nt * 16 + lo;
        b0q[nt] = b0[n]; b1q[nt] = b1[n]; w2q[nt] = w2[n];
    }
    const float b2v = b2[0];
    __syncthreads();

    // ---- layer 1: [64,64] x [64,256] ----
    f32x4 acc1[4][4];
#pragma unroll
    for (int mt = 0; mt < 4; ++mt)
#pragma unroll
        for (int nt = 0; nt < 4; ++nt) acc1[mt][nt] = (f32x4)0.0f;

    short8 ax[4][2];
#pragma unroll
    for (int mt = 0; mt < 4; ++mt)
#pragma unroll
        for (int ks = 0; ks < 2; ++ks) {
            const int row = mt * 16 + lo;
            const int byte = (row * 128 + ks * 64 + g * 16) ^ SWZ(row);
            ax[mt][ks] = *(const short8*)((const char*)x_lds + byte);
        }
#pragma unroll
    for (int mt = 0; mt < 4; ++mt)
#pragma unroll
        for (int nt = 0; nt < 4; ++nt) {
            acc1[mt][nt] = __builtin_amdgcn_mfma_f32_16x16x32_bf16(ax[mt][0], w0q[nt][0], acc1[mt][nt], 0, 0, 0);
            acc1[mt][nt] = __builtin_amdgcn_mfma_f32_16x16x32_bf16(ax[mt][1], w0q[nt][1], acc1[mt][nt], 0, 0, 0);
        }

#pragma unroll
    for (int mt = 0; mt < 4; ++mt)
#pragma unroll
        for (int nt = 0; nt < 4; ++nt) {
            const int n = wave * 64 + nt * 16 + lo;
#pragma unroll
            for (int r = 0; r < 4; ++r) {
                const int row = mt * 16 + g * 4 + r;
                const float hv = fmaxf(acc1[mt][nt][r] + b0q[nt], 0.0f);
                h_lds[((row * 512 + n * 2) ^ SWZ(row)) >> 1] = f2bf(hv);
            }
        }
    __syncthreads();

    // ---- layer 2: [64,256] x [256,256], w1 streamed ----
    f32x4 acc2[4][4];
#pragma unroll
    for (int mt = 0; mt < 4; ++mt)
#pragma unroll
        for (int nt = 0; nt < 4; ++nt) acc2[mt][nt] = (f32x4)0.0f;

#pragma unroll
    for (int ks = 0; ks < 8; ++ks) {
        short8 w1k[4];
#pragma unroll
        for (int nt = 0; nt < 4; ++nt)
            w1k[nt] = *(const short8*)(w1f + (size_t)(((wave * 4 + nt) * 8 + ks) * 64 + lane) * 8);
        short8 ah[4];
#pragma unroll
        for (int mt = 0; mt < 4; ++mt) {
            const int row = mt * 16 + lo;
            const int byte = (row * 512 + ks * 64 + g * 16) ^ SWZ(row);
            ah[mt] = *(const short8*)((const char*)h_lds + byte);
        }
#pragma unroll
        for (int mt = 0; mt < 4; ++mt)
#pragma unroll
            for (int nt = 0; nt < 4; ++nt)
                acc2[mt][nt] = __builtin_amdgcn_mfma_f32_16x16x32_bf16(ah[mt], w1k[nt], acc2[mt][nt], 0, 0, 0);
    }

    // ---- layer 3: relu, dot w2, reduce over 256 cols ----
    float s[4][4];
#pragma unroll
    for (int mt = 0; mt < 4; ++mt)
#pragma unroll
        for (int r = 0; r < 4; ++r) s[mt][r] = 0.0f;
#pragma unroll
    for (int mt = 0; mt < 4; ++mt)
#pragma unroll
        for (int nt = 0; nt < 4; ++nt)
#pragma unroll
            for (int r = 0; r < 4; ++r)
                s[mt][r] += fmaxf(acc2[mt][nt][r] + b1q[nt], 0.0f) * w2q[nt];
#pragma unroll
    for (int mt = 0; mt < 4; ++mt)
#pragma unroll
        for (int r = 0; r < 4; ++r) {
#pragma unroll
            for (int m = 8; m >= 1; m >>= 1)
                s[mt][r] += __shfl_xor(s[mt][r], m, 64);
        }
    if (lo == 0) {
#pragma unroll
        for (int mt = 0; mt < 4; ++mt)
#pragma unroll
            for (int r = 0; r < 4; ++r)
                part[mt * 16 + g * 4 + r][wave] = s[mt][r];
    }
    __syncthreads();
    if (tid < 64)
        pred[m0 + tid] = part[tid][0] + part[tid][1] + part[tid][2] + part[tid][3] + b2v;
}

// ---------------------------------------------------------------------------
// Kernel 5: blend — per (b,p): bilinear BP + pred blend, tree-reduce over v.
// ---------------------------------------------------------------------------
__global__ __launch_bounds__(192) void blend_kernel(
    const float* __restrict__ sino, const float* __restrict__ grid,
    const float* __restrict__ sqinv, const float* __restrict__ pred,
    float* __restrict__ out)
{
    __shared__ float red[192];
    const int tid = threadIdx.x;
    const int b   = blockIdx.x >> 10;
    const int p   = blockIdx.x & 1023;
    const int v   = tid;
    const float S = (float)(1.0 / 384.0 + 1e-6);

    float val = 0.0f;
    if (v < VV) {
        const float* gp = &grid[((size_t)(b * VV + v) * WOUTN + p) * 2];
        const float gx = gp[0], gy = gp[1];
        const float sqv = sqinv[(size_t)(b * VV + v) * WOUTN + p];

        // bilinear back-projection (channel 32)
        float ix = ((gx + 1.0f) * 384.0f - 1.0f) * 0.5f;
        ix = fminf(fmaxf(ix, 0.0f), 383.0f);
        float iy = ((gy + 1.0f) * 180.0f - 1.0f) * 0.5f;
        iy = fminf(fmaxf(iy, 0.0f), 179.0f);
        const float xf = floorf(ix), yf = floorf(iy);
        const float wx = ix - xf, wy = iy - yf;
        const int x0i = (int)xf, y0i = (int)yf;
        const int x1i = min(x0i + 1, 383), y1i = min(y0i + 1, 179);
        const float* im = &sino[(size_t)(b * CC + 32) * VV * DD];
        const float v00 = im[y0i * DD + x0i], v01 = im[y0i * DD + x1i];
        const float v10 = im[y1i * DD + x0i], v11 = im[y1i * DD + x1i];
        const float bp = (v00 * (1.0f - wx) + v01 * wx) * (1.0f - wy)
                       + (v10 * (1.0f - wx) + v11 * wx) * wy;

        // rel/len for both shifts (must match xbuild arithmetic)
        float len[2];
#pragma unroll
        for (int sh = 0; sh < 2; ++sh) {
            const float shv = sh ? S : -S;
            float ixs = ((gx + shv + 1.0f) * 384.0f - 1.0f) * 0.5f;
            ixs = fminf(fmaxf(ixs, 0.0f), 383.0f);
            const int xi = (int)rintf(ixs);
            const float det = (2.0f * (float)xi + 1.0f) / 384.0f - 1.0f;
            const float rel = (gx - det) * 384.0f;
            len[sh] = fabsf(rel) + 1e-4f;
        }
        const size_t e0 = ((size_t)(v * BB + b) * WOUTN + p) * 2;
        const float p0 = pred[e0], p1 = pred[e0 + 1];
        const float ret = (p0 * len[1] + p1 * len[0]) / (len[0] + len[1]);
        val = (bp + ret) * sqv * 10000.0f;
    }
    red[tid] = val;
    __syncthreads();
#pragma unroll
    for (int off = 96; off >= 6; off >>= 1) {
        if (tid < off) red[tid] += red[tid + off];
        __syncthreads();
    }
    if (tid == 0) {
        float r = red[0] + red[1] + red[2] + red[3] + red[4] + red[5];
        out[(size_t)b * WOUTN + p] = r;
    }
}

extern "C" void kernel_launch(void* const* d_in, const int* in_sizes, int n_in,
                              void* d_out, int out_size, void* d_ws, size_t ws_size,
                              hipStream_t stream) {
    const float* sino    = (const float*)d_in[0];
    const float* grid    = (const float*)d_in[1];
    const float* sqinv   = (const float*)d_in[2];
    const void*  scale_p = d_in[3];
    const float* coef_w  = (const float*)d_in[4];
    const float* coef_b  = (const float*)d_in[5];
    const float* freq_w  = (const float*)d_in[6];
    const float* freq_b  = (const float*)d_in[7];
    const float* phase_w = (const float*)d_in[8];
    const float* dec_w0  = (const float*)d_in[9];
    const float* dec_b0  = (const float*)d_in[10];
    const float* dec_w1  = (const float*)d_in[11];
    const float* dec_b1  = (const float*)d_in[12];
    const float* dec_w2  = (const float*)d_in[13];
    const float* dec_b2  = (const float*)d_in[14];
    float* out = (float*)d_out;

    const size_t NPIX = (size_t)BB * VV * DD;              // 138240
    float*          ws_fsum = (float*)d_ws;                // NPIX*32 f32
    unsigned short* coef_bf = (unsigned short*)(ws_fsum + NPIX * 32);  // NPIX*64 bf16
    unsigned short* sino_cl = coef_bf + NPIX * 64;         // NPIX*64 bf16
    unsigned short* w0f = sino_cl + NPIX * 64;             // 16384
    unsigned short* w1f = w0f + 64 * 256;                  // 65536
    unsigned short* wcf = w1f + 256 * 256;                 // 73728
    unsigned short* Xs  = wcf + 576 * 128;                 // EVSL*64 bf16 (slice, reused)
    float*          pred = (float*)(Xs + (size_t)EVSL * 64);  // NSLICE*EVSL f32

    prep_kernel<<<(64 * 256 + 256 * 256 + 576 * 128 + 255) / 256, 256, 0, stream>>>(
        dec_w0, dec_w1, coef_w, freq_w, w0f, w1f, wcf);

    transpose_kernel<<<BB * VV * (DD / 64), 256, 0, stream>>>(sino, sino_cl);

    conv_mfma_kernel<<<BB * VV * (DD / 64), 256, 0, stream>>>(
        sino_cl, wcf, coef_b, freq_b, coef_bf, ws_fsum);

    for (int s = 0; s < NSLICE; ++s) {
        xbuild_kernel<<<EVSL * 4 / 256, 256, 0, stream>>>(
            grid, ws_fsum, coef_bf, scale_p, phase_w, Xs, s * VSL);
        mlp_kernel<<<EVSL / 64, 256, 0, stream>>>(
            Xs, w0f, dec_b0, w1f, dec_b1, dec_w2, dec_b2,
            pred + (size_t)s * EVSL);
    }

    blend_kernel<<<BB * WOUTN, 192, 0, stream>>>(sino, grid, sqinv, pred, out);
}

// Round 6
// 244.887 us; speedup vs baseline: 18.6189x; 1.0483x over previous
//
#include <hip/hip_runtime.h>
#include <math.h>

#define BB    2
#define CC    64
#define VV    180
#define DD    384
#define WOUTN 1024
#define HIDN  256
#define NSLICE 4
#define VSL   45                       // views per slice
#define EVSL  (VSL * BB * WOUTN * 2)   // evals per slice = 184320

typedef __attribute__((ext_vector_type(8))) short short8;   // 8 bf16
typedef __attribute__((ext_vector_type(4))) float f32x4;    // MFMA acc

__device__ __forceinline__ unsigned short f2bf(float f) {
    unsigned int u = __float_as_uint(f);
    u += 0x7FFFu + ((u >> 16) & 1u);   // RNE
    return (unsigned short)(u >> 16);
}
__device__ __forceinline__ float bf2f(unsigned short s) {
    return __uint_as_float(((unsigned int)s) << 16);
}
__device__ __forceinline__ unsigned int pk2bf(float a, float b) {
    return (unsigned int)f2bf(a) | ((unsigned int)f2bf(b) << 16);
}

// ---------------------------------------------------------------------------
// Kernel 0: weight prep (MLP w0/w1 + combined conv weights -> bf16 fragments)
// Fragment layout is symmetric for A/B operands, so w0f/w1f also serve as
// A-fragments of W0^T / W1^T (operand-swapped MFMA).
// ---------------------------------------------------------------------------
__global__ __launch_bounds__(256) void prep_kernel(
    const float* __restrict__ w0, const float* __restrict__ w1,
    const float* __restrict__ wc, const float* __restrict__ wf,
    unsigned short* __restrict__ w0f, unsigned short* __restrict__ w1f,
    unsigned short* __restrict__ wcf)
{
    int idx = blockIdx.x * 256 + threadIdx.x;
    if (idx < 64 * 256) {
        int k = idx >> 8, n = idx & 255;
        int wave = n >> 6, nt = (n >> 4) & 3, lo = n & 15;
        int ks = k >> 5, hi = (k >> 3) & 3, j = k & 7;
        w0f[(size_t)(((wave * 4 + nt) * 2 + ks) * 64 + hi * 16 + lo) * 8 + j] =
            f2bf(w0[k * 256 + n]);
    } else if (idx < 64 * 256 + 256 * 256) {
        int i2 = idx - 64 * 256;
        int k = i2 >> 8, n = i2 & 255;
        int wave = n >> 6, nt = (n >> 4) & 3, lo = n & 15;
        int ks = k >> 5, hi = (k >> 3) & 3, j = k & 7;
        w1f[(size_t)(((wave * 4 + nt) * 8 + ks) * 64 + hi * 16 + lo) * 8 + j] =
            f2bf(w1[k * 256 + n]);
    } else if (idx < 64 * 256 + 256 * 256 + 576 * 128) {
        int i3 = idx - (64 * 256 + 256 * 256);
        int k = i3 >> 7, n = i3 & 127;
        int tap = k >> 6, ic = k & 63;
        int r = tap / 3, t = tap - r * 3;
        int head = n >> 6, oc = n & 63;
        float val = (head ? wf : wc)[((oc * 64 + ic) * 3 + r) * 3 + t];
        int ks = k >> 5, hi = (k >> 3) & 3, j = k & 7;
        int nt = n >> 4, lo = n & 15;
        wcf[(size_t)((ks * 8 + nt) * 64 + hi * 16 + lo) * 8 + j] = f2bf(val);
    }
}

// ---------------------------------------------------------------------------
// Kernel 1: transpose sinogram [b,c,y,x] f32 -> channel-last bf16 [b,y,x,c]
// ---------------------------------------------------------------------------
__global__ __launch_bounds__(256) void transpose_kernel(
    const float* __restrict__ sino, unsigned short* __restrict__ sino_cl)
{
    __shared__ float tile[64][65];
    const int blk = blockIdx.x;
    const int xt = blk % 6;
    const int y  = (blk / 6) % VV;
    const int b  = blk / (6 * VV);
    const int x0 = xt * 64;

    const int x  = threadIdx.x & 63;
    const int cq = threadIdx.x >> 6;
#pragma unroll
    for (int cr = 0; cr < 16; ++cr) {
        const int c = cr * 4 + cq;
        tile[c][x] = sino[((size_t)(b * CC + c) * VV + y) * DD + x0 + x];
    }
    __syncthreads();

    const int xw = threadIdx.x >> 2;
    const int cg = threadIdx.x & 3;
    __align__(16) unsigned short vals[16];
#pragma unroll
    for (int i = 0; i < 16; ++i) vals[i] = f2bf(tile[cg * 16 + i][xw]);
    unsigned short* dst = sino_cl + ((size_t)(b * VV + y) * DD + x0 + xw) * 64 + cg * 16;
    *(short8*)dst       = *(const short8*)&vals[0];
    *((short8*)dst + 1) = *(const short8*)&vals[8];
}

// ---------------------------------------------------------------------------
// Kernel 2: conv as implicit GEMM via MFMA. coef out bf16. (unchanged)
// ---------------------------------------------------------------------------
#define SWZ(x) (((x) & 7) << 4)

__global__ __launch_bounds__(256) void conv_mfma_kernel(
    const unsigned short* __restrict__ sino_cl,
    const unsigned short* __restrict__ wcf,
    const float* __restrict__ bc, const float* __restrict__ bf,
    unsigned short* __restrict__ out_coef, float* __restrict__ out_fsum)
{
    __shared__ __align__(16) unsigned short a_lds[3 * 66 * 64];
    const int blk = blockIdx.x;
    const int xt = blk % 6;
    const int y  = (blk / 6) % VV;
    const int b  = blk / (6 * VV);
    const int x0 = xt * 64;
    const int tid  = threadIdx.x;
    const int wave = tid >> 6;
    const int lane = tid & 63;
    const int lo   = lane & 15;
    const int g    = lane >> 4;

    for (int cc = tid; cc < 1584; cc += 256) {
        const int r   = cc / 528;
        const int rem = cc - r * 528;
        const int x   = rem >> 3;
        const int icg = rem & 7;
        const int gy  = y + r - 1;
        const int gx  = x0 + x - 1;
        short8 v = (short8)0;
        if (gy >= 0 && gy < VV && gx >= 0 && gx < DD)
            v = *(const short8*)(sino_cl + ((size_t)(b * VV + gy) * DD + gx) * 64 + icg * 8);
        const int dst = ((r * 66 + x) * 128 + icg * 16) ^ SWZ(x);
        *(short8*)((char*)a_lds + dst) = v;
    }
    __syncthreads();

    f32x4 acc[4][2];
#pragma unroll
    for (int m = 0; m < 4; ++m) {
        acc[m][0] = (f32x4)0.0f;
        acc[m][1] = (f32x4)0.0f;
    }

#pragma unroll
    for (int ks = 0; ks < 18; ++ks) {
        const int tap = ks >> 1;
        const int r = tap / 3, t = tap - (tap / 3) * 3;
        const short8 wq0 = *(const short8*)(wcf + (size_t)((ks * 8 + wave * 2 + 0) * 64 + lane) * 8);
        const short8 wq1 = *(const short8*)(wcf + (size_t)((ks * 8 + wave * 2 + 1) * 64 + lane) * 8);
        short8 aq[4];
#pragma unroll
        for (int m = 0; m < 4; ++m) {
            const int x = m * 16 + lo + t;
            const int byte = ((r * 66 + x) * 128 + ((ks & 1) * 64 + g * 16)) ^ SWZ(x);
            aq[m] = *(const short8*)((const char*)a_lds + byte);
        }
#pragma unroll
        for (int m = 0; m < 4; ++m) {
            acc[m][0] = __builtin_amdgcn_mfma_f32_16x16x32_bf16(aq[m], wq0, acc[m][0], 0, 0, 0);
            acc[m][1] = __builtin_amdgcn_mfma_f32_16x16x32_bf16(aq[m], wq1, acc[m][1], 0, 0, 0);
        }
    }

    const size_t pixbase = (size_t)(b * VV + y) * DD + x0;
    if (wave < 2) {
#pragma unroll
        for (int nt = 0; nt < 2; ++nt) {
            const int oc = wave * 32 + nt * 16 + lo;
            const float bias = bc[oc];
#pragma unroll
            for (int m = 0; m < 4; ++m)
#pragma unroll
                for (int ri = 0; ri < 4; ++ri) {
                    const int pix = m * 16 + g * 4 + ri;
                    out_coef[(pixbase + pix) * 64 + oc] = f2bf(acc[m][nt][ri] + bias);
                }
        }
    } else {
#pragma unroll
        for (int nt = 0; nt < 2; ++nt) {
            const int ocf = (wave - 2) * 32 + nt * 16 + lo;
            const float bsum = bf[ocf] + bf[ocf ^ 1];
#pragma unroll
            for (int m = 0; m < 4; ++m)
#pragma unroll
                for (int ri = 0; ri < 4; ++ri) {
                    const float v  = acc[m][nt][ri];
                    const float vp = __shfl_xor(v, 1, 64);
                    if ((lo & 1) == 0) {
                        const int pix = m * 16 + g * 4 + ri;
                        out_fsum[(pixbase + pix) * 32 + (ocf >> 1)] = v + vp + bsum;
                    }
                }
        }
    }
}

// ---------------------------------------------------------------------------
// Kernel 3: xbuild — gather + trig, 4 threads per eval. (unchanged)
// ---------------------------------------------------------------------------
__global__ __launch_bounds__(256) void xbuild_kernel(
    const float* __restrict__ grid, const float* __restrict__ fsum,
    const unsigned short* __restrict__ coef_bf,
    const void* __restrict__ scale_p, const float* __restrict__ phase_w,
    unsigned short* __restrict__ X, int vbase)
{
    const int t  = blockIdx.x * 256 + threadIdx.x;
    const int el = t >> 2;
    const int q  = t & 3;

    const int sh = el & 1;
    const int p  = (el >> 1) & 1023;
    const int b  = (el >> 11) & 1;
    const int vl = el >> 12;
    const int v  = vbase + vl;

    int   iv = *(const int*)scale_p;
    float scale = (iv > 0 && iv < 1000000) ? (float)iv : __int_as_float(iv);
    const float cell = 2.0f / scale;
    const float S = (float)(1.0 / 384.0 + 1e-6);
    const float shv = sh ? S : -S;

    const float* gp = &grid[((size_t)(b * VV + v) * WOUTN + p) * 2];
    const float gx = gp[0], gy = gp[1];
    float ix = ((gx + shv + 1.0f) * 384.0f - 1.0f) * 0.5f;
    ix = fminf(fmaxf(ix, 0.0f), 383.0f);
    const int xi = (int)rintf(ix);
    float iy = ((gy + 1.0f) * 180.0f - 1.0f) * 0.5f;
    iy = fminf(fmaxf(iy, 0.0f), 179.0f);
    const int yi = (int)rintf(iy);
    const float det = (2.0f * (float)xi + 1.0f) / 384.0f - 1.0f;
    const float rel = (gx - det) * 384.0f;
    const int base = (b * VV + yi) * DD + xi;

    const int j0 = q * 8;
    const float4 fsa = *(const float4*)(fsum + (size_t)base * 32 + j0);
    const float4 fsb = *(const float4*)(fsum + (size_t)base * 32 + j0 + 4);
    const short8 c0 = *(const short8*)(coef_bf + (size_t)base * 64 + j0);
    const short8 c1 = *(const short8*)(coef_bf + (size_t)base * 64 + 32 + j0);
    const float4 pha = *(const float4*)(phase_w + j0);
    const float4 phb = *(const float4*)(phase_w + j0 + 4);

    float fs[8] = {fsa.x, fsa.y, fsa.z, fsa.w, fsb.x, fsb.y, fsb.z, fsb.w};
    float ph[8] = {pha.x, pha.y, pha.z, pha.w, phb.x, phb.y, phb.z, phb.w};

    __align__(16) unsigned short xc[8], xs[8];
#pragma unroll
    for (int jj = 0; jj < 8; ++jj) {
        const float fr = rel * fs[jj] + cell * ph[jj];
        xc[jj] = f2bf(bf2f((unsigned short)c0[jj]) * cospif(fr));
        xs[jj] = f2bf(bf2f((unsigned short)c1[jj]) * sinpif(fr));
    }
    *(short8*)(X + (size_t)el * 64 + j0)      = *(const short8*)xc;
    *(short8*)(X + (size_t)el * 64 + 32 + j0) = *(const short8*)xs;
}

// ---------------------------------------------------------------------------
// Kernel 4: mlp v2 — operand-swapped MFMA (compute transposed layers).
//   layer1: H^T = W0^T·X^T  (w0f frags as A, X rows as B) -> in-lane regs are
//           4 consecutive HIDDEN rows -> packed b64 writes to h_t[k/8][eval][8]
//   layer2: C2^T = W1^T·H^T (w1f frags as A, h_t b128 reads as B)
//   layer3: reduction over hidden2 is in-lane (4 mt x 4 r) + 2 shfl_xor.
// ---------------------------------------------------------------------------
__global__ __launch_bounds__(256, 2) void mlp_kernel(
    const unsigned short* __restrict__ X,
    const unsigned short* __restrict__ w0f, const float* __restrict__ b0,
    const unsigned short* __restrict__ w1f, const float* __restrict__ b1,
    const float* __restrict__ w2, const float* __restrict__ b2,
    float* __restrict__ pred)
{
    const int tid  = threadIdx.x;
    const int wave = tid >> 6;
    const int lane = tid & 63;
    const int lo   = lane & 15;
    const int g    = lane >> 4;
    const int m0   = blockIdx.x * 64;

    __shared__ __align__(16) unsigned short x_lds[64 * 64];      // 8 KB
    __shared__ __align__(16) unsigned short h_t[32 * 64 * 8];    // 32 KB [k/8][eval][8]
    __shared__ float part[64][4];

    // ---- stage X tile (swizzled rows) ----
#pragma unroll
    for (int it = 0; it < 2; ++it) {
        const int idx = it * 256 + tid;
        const int row = idx >> 3;
        const int c   = idx & 7;
        const short8 vv = *(const short8*)(X + (size_t)(m0 + row) * 64 + c * 8);
        const int dst = (row * 128 + c * 16) ^ SWZ(row);
        *(short8*)((char*)x_lds + dst) = vv;
    }

    // ---- W0^T A-frags (wave owns hidden rows wave*64..+63) ----
    short8 w0q[4][2];
#pragma unroll
    for (int mt = 0; mt < 4; ++mt)
#pragma unroll
        for (int ks = 0; ks < 2; ++ks)
            w0q[mt][ks] = *(const short8*)(w0f + (size_t)(((wave * 4 + mt) * 2 + ks) * 64 + lane) * 8);

    // ---- biases/w2 indexed by this lane's hidden rows (g*4..g*4+3) ----
    float4 b0h[4], b1h[4], w2h[4];
#pragma unroll
    for (int mt = 0; mt < 4; ++mt) {
        const int h = wave * 64 + mt * 16 + g * 4;
        b0h[mt] = *(const float4*)(b0 + h);
        b1h[mt] = *(const float4*)(b1 + h);
        w2h[mt] = *(const float4*)(w2 + h);
    }
    const float b2v = b2[0];
    __syncthreads();

    // ---- layer 1: H^T = W0^T · X^T ----
    f32x4 acc1[4][4];
#pragma unroll
    for (int mt = 0; mt < 4; ++mt)
#pragma unroll
        for (int nt = 0; nt < 4; ++nt) acc1[mt][nt] = (f32x4)0.0f;

    short8 bx[4][2];
#pragma unroll
    for (int nt = 0; nt < 4; ++nt)
#pragma unroll
        for (int ks = 0; ks < 2; ++ks) {
            const int row = nt * 16 + lo;
            const int byte = (row * 128 + ks * 64 + g * 16) ^ SWZ(row);
            bx[nt][ks] = *(const short8*)((const char*)x_lds + byte);
        }
#pragma unroll
    for (int mt = 0; mt < 4; ++mt)
#pragma unroll
        for (int nt = 0; nt < 4; ++nt) {
            acc1[mt][nt] = __builtin_amdgcn_mfma_f32_16x16x32_bf16(w0q[mt][0], bx[nt][0], acc1[mt][nt], 0, 0, 0);
            acc1[mt][nt] = __builtin_amdgcn_mfma_f32_16x16x32_bf16(w0q[mt][1], bx[nt][1], acc1[mt][nt], 0, 0, 0);
        }

    // ---- bias+relu, pack 4 hidden rows -> one b64 write ----
    // lane holds H^T[hidden = wave*64+mt*16+g*4+r][eval = nt*16+lo]
    // h_t layout: [kb2 = k/8][eval][8] ; this lane's 4 values are half of kb2
#pragma unroll
    for (int mt = 0; mt < 4; ++mt) {
        const int kb2  = (wave * 16 + mt * 4 + g) >> 1;  // k/8
        const int half = (g & 1) * 8;                     // byte offset within 16B
#pragma unroll
        for (int nt = 0; nt < 4; ++nt) {
            const float h0 = fmaxf(acc1[mt][nt][0] + b0h[mt].x, 0.0f);
            const float h1 = fmaxf(acc1[mt][nt][1] + b0h[mt].y, 0.0f);
            const float h2 = fmaxf(acc1[mt][nt][2] + b0h[mt].z, 0.0f);
            const float h3 = fmaxf(acc1[mt][nt][3] + b0h[mt].w, 0.0f);
            uint2 pk;
            pk.x = pk2bf(h0, h1);
            pk.y = pk2bf(h2, h3);
            const int byte = (kb2 * 64 + nt * 16 + lo) * 16 + half;
            *(uint2*)((char*)h_t + byte) = pk;
        }
    }
    __syncthreads();

    // ---- layer 2: C2^T = W1^T · H^T (w1 frags streamed from L2) ----
    f32x4 acc2[4][4];
#pragma unroll
    for (int mt = 0; mt < 4; ++mt)
#pragma unroll
        for (int nt = 0; nt < 4; ++nt) acc2[mt][nt] = (f32x4)0.0f;

#pragma unroll
    for (int ks = 0; ks < 8; ++ks) {
        short8 w1k[4];
#pragma unroll
        for (int mt = 0; mt < 4; ++mt)
            w1k[mt] = *(const short8*)(w1f + (size_t)(((wave * 4 + mt) * 8 + ks) * 64 + lane) * 8);
        short8 bh[4];
#pragma unroll
        for (int nt = 0; nt < 4; ++nt) {
            const int byte = ((ks * 4 + g) * 64 + nt * 16 + lo) * 16;   // linear b128
            bh[nt] = *(const short8*)((const char*)h_t + byte);
        }
#pragma unroll
        for (int mt = 0; mt < 4; ++mt)
#pragma unroll
            for (int nt = 0; nt < 4; ++nt)
                acc2[mt][nt] = __builtin_amdgcn_mfma_f32_16x16x32_bf16(w1k[mt], bh[nt], acc2[mt][nt], 0, 0, 0);
    }

    // ---- layer 3: hidden2 reduce (in-lane over mt,r; cross-lane over g) ----
#pragma unroll
    for (int nt = 0; nt < 4; ++nt) {
        float s = 0.0f;
#pragma unroll
        for (int mt = 0; mt < 4; ++mt) {
            s += fmaxf(acc2[mt][nt][0] + b1h[mt].x, 0.0f) * w2h[mt].x;
            s += fmaxf(acc2[mt][nt][1] + b1h[mt].y, 0.0f) * w2h[mt].y;
            s += fmaxf(acc2[mt][nt][2] + b1h[mt].z, 0.0f) * w2h[mt].z;
            s += fmaxf(acc2[mt][nt][3] + b1h[mt].w, 0.0f) * w2h[mt].w;
        }
        s += __shfl_xor(s, 16, 64);
        s += __shfl_xor(s, 32, 64);
        if (g == 0) part[nt * 16 + lo][wave] = s;
    }
    __syncthreads();
    if (tid < 64)
        pred[m0 + tid] = part[tid][0] + part[tid][1] + part[tid][2] + part[tid][3] + b2v;
}

// ---------------------------------------------------------------------------
// Kernel 5: blend — per (b,p): bilinear BP + pred blend, tree-reduce over v.
// ---------------------------------------------------------------------------
__global__ __launch_bounds__(192) void blend_kernel(
    const float* __restrict__ sino, const float* __restrict__ grid,
    const float* __restrict__ sqinv, const float* __restrict__ pred,
    float* __restrict__ out)
{
    __shared__ float red[192];
    const int tid = threadIdx.x;
    const int b   = blockIdx.x >> 10;
    const int p   = blockIdx.x & 1023;
    const int v   = tid;
    const float S = (float)(1.0 / 384.0 + 1e-6);

    float val = 0.0f;
    if (v < VV) {
        const float* gp = &grid[((size_t)(b * VV + v) * WOUTN + p) * 2];
        const float gx = gp[0], gy = gp[1];
        const float sqv = sqinv[(size_t)(b * VV + v) * WOUTN + p];

        float ix = ((gx + 1.0f) * 384.0f - 1.0f) * 0.5f;
        ix = fminf(fmaxf(ix, 0.0f), 383.0f);
        float iy = ((gy + 1.0f) * 180.0f - 1.0f) * 0.5f;
        iy = fminf(fmaxf(iy, 0.0f), 179.0f);
        const float xf = floorf(ix), yf = floorf(iy);
        const float wx = ix - xf, wy = iy - yf;
        const int x0i = (int)xf, y0i = (int)yf;
        const int x1i = min(x0i + 1, 383), y1i = min(y0i + 1, 179);
        const float* im = &sino[(size_t)(b * CC + 32) * VV * DD];
        const float v00 = im[y0i * DD + x0i], v01 = im[y0i * DD + x1i];
        const float v10 = im[y1i * DD + x0i], v11 = im[y1i * DD + x1i];
        const float bp = (v00 * (1.0f - wx) + v01 * wx) * (1.0f - wy)
                       + (v10 * (1.0f - wx) + v11 * wx) * wy;

        float len[2];
#pragma unroll
        for (int sh = 0; sh < 2; ++sh) {
            const float shv = sh ? S : -S;
            float ixs = ((gx + shv + 1.0f) * 384.0f - 1.0f) * 0.5f;
            ixs = fminf(fmaxf(ixs, 0.0f), 383.0f);
            const int xi = (int)rintf(ixs);
            const float det = (2.0f * (float)xi + 1.0f) / 384.0f - 1.0f;
            const float rel = (gx - det) * 384.0f;
            len[sh] = fabsf(rel) + 1e-4f;
        }
        const size_t e0 = ((size_t)(v * BB + b) * WOUTN + p) * 2;
        const float p0 = pred[e0], p1 = pred[e0 + 1];
        const float ret = (p0 * len[1] + p1 * len[0]) / (len[0] + len[1]);
        val = (bp + ret) * sqv * 10000.0f;
    }
    red[tid] = val;
    __syncthreads();
#pragma unroll
    for (int off = 96; off >= 6; off >>= 1) {
        if (tid < off) red[tid] += red[tid + off];
        __syncthreads();
    }
    if (tid == 0) {
        float r = red[0] + red[1] + red[2] + red[3] + red[4] + red[5];
        out[(size_t)b * WOUTN + p] = r;
    }
}

extern "C" void kernel_launch(void* const* d_in, const int* in_sizes, int n_in,
                              void* d_out, int out_size, void* d_ws, size_t ws_size,
                              hipStream_t stream) {
    const float* sino    = (const float*)d_in[0];
    const float* grid    = (const float*)d_in[1];
    const float* sqinv   = (const float*)d_in[2];
    const void*  scale_p = d_in[3];
    const float* coef_w  = (const float*)d_in[4];
    const float* coef_b  = (const float*)d_in[5];
    const float* freq_w  = (const float*)d_in[6];
    const float* freq_b  = (const float*)d_in[7];
    const float* phase_w = (const float*)d_in[8];
    const float* dec_w0  = (const float*)d_in[9];
    const float* dec_b0  = (const float*)d_in[10];
    const float* dec_w1  = (const float*)d_in[11];
    const float* dec_b1  = (const float*)d_in[12];
    const float* dec_w2  = (const float*)d_in[13];
    const float* dec_b2  = (const float*)d_in[14];
    float* out = (float*)d_out;

    const size_t NPIX = (size_t)BB * VV * DD;              // 138240
    float*          ws_fsum = (float*)d_ws;                // NPIX*32 f32
    unsigned short* coef_bf = (unsigned short*)(ws_fsum + NPIX * 32);  // NPIX*64 bf16
    unsigned short* sino_cl = coef_bf + NPIX * 64;         // NPIX*64 bf16
    unsigned short* w0f = sino_cl + NPIX * 64;             // 16384
    unsigned short* w1f = w0f + 64 * 256;                  // 65536
    unsigned short* wcf = w1f + 256 * 256;                 // 73728
    unsigned short* Xs  = wcf + 576 * 128;                 // EVSL*64 bf16 (slice, reused)
    float*          pred = (float*)(Xs + (size_t)EVSL * 64);  // NSLICE*EVSL f32

    prep_kernel<<<(64 * 256 + 256 * 256 + 576 * 128 + 255) / 256, 256, 0, stream>>>(
        dec_w0, dec_w1, coef_w, freq_w, w0f, w1f, wcf);

    transpose_kernel<<<BB * VV * (DD / 64), 256, 0, stream>>>(sino, sino_cl);

    conv_mfma_kernel<<<BB * VV * (DD / 64), 256, 0, stream>>>(
        sino_cl, wcf, coef_b, freq_b, coef_bf, ws_fsum);

    for (int s = 0; s < NSLICE; ++s) {
        xbuild_kernel<<<EVSL * 4 / 256, 256, 0, stream>>>(
            grid, ws_fsum, coef_bf, scale_p, phase_w, Xs, s * VSL);
        mlp_kernel<<<EVSL / 64, 256, 0, stream>>>(
            Xs, w0f, dec_b0, w1f, dec_b1, dec_w2, dec_b2,
            pred + (size_t)s * EVSL);
    }

    blend_kernel<<<BB * WOUTN, 192, 0, stream>>>(sino, grid, sqinv, pred, out);
}